// Round 7
// baseline (5332.997 us; speedup 1.0000x reference)
//
#include <hip/hip_runtime.h>
#include <hip/hip_bf16.h>

typedef __hip_bfloat16 bf16;
typedef __attribute__((ext_vector_type(8))) short short8x;
typedef __attribute__((ext_vector_type(4))) float f32x4;
typedef __attribute__((ext_vector_type(4))) unsigned int uint4x;

#define NV 110592           // 48^3
#define NVLL 110592ull

__device__ inline float ldmix(const void* p, size_t i, int f){
  return f ? ((const float*)p)[i] : __bfloat162float(((const bf16*)p)[i]);
}
__device__ inline float lo2f(unsigned int u){ union{unsigned int i; float f;} t; t.i = u<<16; return t.f; }
__device__ inline float hi2f(unsigned int u){ union{unsigned int i; float f;} t; t.i = u & 0xffff0000u; return t.f; }
__device__ inline unsigned short bfb(float f){ bf16 h=__float2bfloat16(f); unsigned short u; __builtin_memcpy(&u,&h,2); return u; }
__device__ inline unsigned int pk2(float a, float b){ return (unsigned int)bfb(a) | ((unsigned int)bfb(b)<<16); }

// ---------------- workspace layout (BYTES), total <= 96 MiB ----------------
static const size_t BOFF_O1 = 2621440;
static const size_t BOFF_O2 = 45088768;
static const size_t BOFF_SP = 87556096;
static const size_t SLOT48  = 10616832;
// small-region float offsets
#define SM_P1   0
#define SM_P2   41472
#define SM_PKV  82944
#define SM_A1   124416
#define SM_A2   165888
#define SM_ST   207360
#define SM_W    208064

// fp32 weight region offsets (floats, relative to W)
#define W_UPW   0
#define W_UPB   16384
#define W_WF    16416
#define W_BF    19488
#define W_W1    19536
#define W_B1    21072
#define W_W2    21120
#define W_B2    22656
#define W_W3    22704
#define W_B3    25008
#define W_W4    25056
#define W_B4    27360
#define W_GNG   27408
#define W_GNB   27456
#define W_ATT   27504
#define W_WFIN  46320
#define W_BFIN  52464
#define W_C0W   52528
#define W_C0B   107824
#define W_C1W   107856
#define W_C1B   135504
#define W_TOTAL 135536
#define W_W1P   135536   // [8][48][64]
#define W_B1F   160112
#define W_WFP   160160   // [8][48][64]
#define W_BFF   184736
#define W_WP    184784   // fp32 [32 oc][96 k][27 tap]
#define W_TB    267728   // fp32 [27 tap][32 oc]
#define W_WB1   268592   // bf16[82944]  conv3 #1 frags
#define W_WB2   310064   // bf16[27648]  conv3 #2 frags
#define W_WB3   323888   // bf16[1536]   W2 frags (K=32)
#define W_WB4   324656   // bf16[3072]   W3 frags (K=48 padded)
#define W_WB5   326192   // bf16[3072]   W4 frags (K=48 padded)
#define W_WBI   327728   // bf16[24576]  W1P frags [8 par][2 kt][3 nt]
#define SM_FL   600000

// ---------------- dtype detect ----------------
__global__ __launch_bounds__(256) void k_detect(const void* xe, float* __restrict__ flag){
  const bf16* p = (const bf16*)xe;
  int tid = threadIdx.x;
  float mx = 0.f;
  for(int i=tid;i<8192;i+=256){
    float v = fabsf(__bfloat162float(p[i]));
    if(!(v==v)) v = 1e30f;
    mx = fmaxf(mx, v);
  }
  #pragma unroll
  for(int s=32;s>=1;s>>=1) mx = fmaxf(mx, __shfl_xor(mx,s));
  __shared__ float red[4];
  if((tid&63)==0) red[tid>>6] = mx;
  __syncthreads();
  if(tid==0){
    float m = fmaxf(fmaxf(red[0],red[1]), fmaxf(red[2],red[3]));
    flag[0] = (m > 1e3f) ? 1.f : 0.f;
  }
}

__global__ __launch_bounds__(256) void k_zero(float* __restrict__ st){
  int i = blockIdx.x*256 + threadIdx.x;
  if(i < 704) st[i] = 0.f;
}

// ---------------- weight prep ----------------
struct PtrTab { const void* p[36]; };
__device__ const int g_seg[36] = {16384,32,3072,48,1536,48,1536,48,2304,48,2304,48,48,48,
  2304,48,2304,48,2304,48,2304,48,2304,48,2304,48,2304,48,2304,48,6144,64,55296,32,27648,32};

__global__ __launch_bounds__(256) void k_prep(PtrTab t, float* __restrict__ W, const float* __restrict__ flag){
  const int f = (int)flag[0];
  int i = blockIdx.x*256 + threadIdx.x;
  if(i >= W_TOTAL) return;
  int rem = i;
  for(int s=0;s<36;s++){
    int sz = g_seg[s];
    if(rem < sz){ W[i] = ldmix(t.p[s], rem, f); return; }
    rem -= sz;
  }
}

__global__ __launch_bounds__(256) void k_fold(float* __restrict__ W){
  int i = blockIdx.x*256 + threadIdx.x;
  const float* upw = W + W_UPW;
  const float* upb = W + W_UPB;
  if(i < 49152){
    int which = i / 24576;
    int r = i % 24576;
    int par = r / 3072; int o = (r/64)%48; int c = r%64;
    float acc = 0.f;
    for(int m=0;m<32;m++){
      float wm = which ? W[W_WF + o*64 + 32 + m] : W[W_W1 + o*32 + m];
      acc += wm * upw[c*256 + m*8 + par];
    }
    W[(which ? W_WFP : W_W1P) + par*3072 + o*64 + c] = acc;
  } else if(i < 49248){
    int j = i - 49152;
    int which = j / 48; int o = j % 48;
    float acc = which ? W[W_BF + o] : W[W_B1 + o];
    for(int m=0;m<32;m++){
      float wm = which ? W[W_WF + o*64 + 32 + m] : W[W_W1 + o*32 + m];
      acc += wm * upb[m];
    }
    W[(which ? W_BFF : W_B1F) + o] = acc;
  }
}

__global__ __launch_bounds__(256) void k_fold2(float* __restrict__ W){
  int i = blockIdx.x*256 + threadIdx.x;
  if(i < 82944){
    int tap = i%27; int k = (i/27)%96; int oc = i/(27*96);
    float acc = 0.f;
    for(int m=0;m<64;m++) acc += W[W_C0W + oc*1728 + m*27 + tap] * W[W_WFIN + m*96 + k];
    W[W_WP + i] = acc;
  } else if(i < 83808){
    int j = i - 82944;
    int tap = j/32, oc = j%32;
    float acc = 0.f;
    for(int m=0;m<64;m++) acc += W[W_C0W + oc*1728 + m*27 + tap] * W[W_BFIN + m];
    W[W_TB + tap*32 + oc] = acc;
  }
}

__global__ __launch_bounds__(256) void k_packb1(float* __restrict__ W){
  int i = blockIdx.x*256 + threadIdx.x;
  if(i >= 82944) return;
  int j = i&7; int lane = (i>>3)&63; int frag = i>>9;
  int nt = frag&1; int tkt = frag>>1; int kt = tkt%3; int tap = tkt/3;
  int oc = nt*16 + (lane&15);
  int k  = kt*32 + ((lane>>4)<<3) + j;
  ((bf16*)(W + W_WB1))[i] = __float2bfloat16(W[W_WP + oc*2592 + k*27 + tap]);
}
__global__ __launch_bounds__(256) void k_packb2(float* __restrict__ W){
  int i = blockIdx.x*256 + threadIdx.x;
  if(i >= 27648) return;
  int j = i&7; int lane = (i>>3)&63; int frag = i>>9;
  int nt = frag&1; int tap = frag>>1;
  int oc = nt*16 + (lane&15);
  int ic = ((lane>>4)<<3) + j;
  ((bf16*)(W + W_WB2))[i] = __float2bfloat16(W[W_C1W + oc*864 + ic*27 + tap]);
}

// pack generic 1x1 weights [48][cin] -> B frags [kt][nt][lane][8], K zero-padded
__global__ __launch_bounds__(256) void k_packc(float* __restrict__ W, int srcoff, int cin, int ktc, int dstoff){
  int i = blockIdx.x*256 + threadIdx.x;
  if(i >= ktc*1536) return;
  int j=i&7, lane=(i>>3)&63, frag=i>>9;
  int nt = frag%3, kt = frag/3;
  int oc = nt*16 + (lane&15);
  int k  = kt*32 + ((lane>>4)<<3) + j;
  float v = (k < cin) ? W[srcoff + oc*cin + k] : 0.f;
  ((bf16*)(W + dstoff))[i] = __float2bfloat16(v);
}
// pack W1P [8 par][48 oc][64 c] -> frags [par][kt][nt][lane][8]
__global__ __launch_bounds__(256) void k_packi1(float* __restrict__ W){
  int i = blockIdx.x*256 + threadIdx.x;
  if(i >= 24576) return;
  int j=i&7, lane=(i>>3)&63, frag=i>>9;   // frag 0..47
  int par = frag/6, rem = frag%6;
  int kt = rem/3, nt = rem%3;
  int oc = nt*16 + (lane&15);
  int k  = kt*32 + ((lane>>4)<<3) + j;
  ((bf16*)(W + W_WBI))[i] = __float2bfloat16(W[W_W1P + par*3072 + oc*64 + k]);
}

// ---------------- i1 MFMA: folded deconv+w1, x (NCDHW mix) -> O1 NHWC 48ch + stats set0
__global__ __launch_bounds__(256) void k_i1mm(const void* __restrict__ x, const float* __restrict__ W,
    bf16* __restrict__ out, float* __restrict__ stato, const float* __restrict__ flag)
{
  const int f = (int)flag[0];
  const int tid = threadIdx.x, wid = tid>>6, lane = tid&63;
  const int w = blockIdx.x*4 + wid;            // < 3456
  const int b = w/864, t = w%864;
  const int vc0 = t*16;                        // coarse voxel base (13824 per batch)
  const int m = lane&15, quad = lane>>4;
  const short8x* wbI = (const short8x*)(W + W_WBI);

  // A frags (hi/lo) for kt=0,1 over K=64
  short8x ah[2], al[2];
  #pragma unroll
  for(int kt=0;kt<2;kt++){
    short hh[8], ll[8];
    #pragma unroll
    for(int j=0;j<8;j++){
      int k = kt*32 + quad*8 + j;
      float v = ldmix(x, ((size_t)(b*64 + k))*13824 + vc0 + m, f);
      bf16 h = __float2bfloat16(v);
      float hf = __bfloat162float(h);
      bf16 l = __float2bfloat16(v - hf);
      __builtin_memcpy(&hh[j], &h, 2); __builtin_memcpy(&ll[j], &l, 2);
    }
    __builtin_memcpy(&ah[kt], hh, 16); __builtin_memcpy(&al[kt], ll, 16);
  }

  f32x4 acc[8][3];
  #pragma unroll
  for(int p=0;p<8;p++)
    #pragma unroll
    for(int nt=0;nt<3;nt++) acc[p][nt] = (f32x4){0.f,0.f,0.f,0.f};

  #pragma unroll
  for(int par=0;par<8;par++){
    #pragma unroll
    for(int kt=0;kt<2;kt++){
      #pragma unroll
      for(int nt=0;nt<3;nt++){
        short8x bfr = wbI[(size_t)((par*2+kt)*3+nt)*64 + lane];
        acc[par][nt] = __builtin_amdgcn_mfma_f32_16x16x32_bf16(ah[kt], bfr, acc[par][nt], 0,0,0);
        acc[par][nt] = __builtin_amdgcn_mfma_f32_16x16x32_bf16(al[kt], bfr, acc[par][nt], 0,0,0);
      }
    }
  }

  // epilogue: bias + stats + LDS repack -> vector global stores
  __shared__ bf16 lds[4][128][48];
  const float* bp = W + W_B1F;
  float sl[3] = {0,0,0}, ssl[3] = {0,0,0};
  #pragma unroll
  for(int nt=0;nt<3;nt++){
    int oc = nt*16 + m;                        // D col = oc
    float bias = bp[oc];
    #pragma unroll
    for(int par=0;par<8;par++){
      #pragma unroll
      for(int r=0;r<4;r++){
        float v = acc[par][nt][r] + bias;
        int vid = (quad*4+r)*8 + par;          // D row = coarse voxel in tile
        lds[wid][vid][oc] = __float2bfloat16(v);
        sl[nt] += v; ssl[nt] += v*v;
      }
    }
  }
  #pragma unroll
  for(int nt=0;nt<3;nt++){
    float a = sl[nt], s2 = ssl[nt];
    a += __shfl_xor(a,16); s2 += __shfl_xor(s2,16);
    a += __shfl_xor(a,32); s2 += __shfl_xor(s2,32);
    a += __shfl_xor(a,1);  s2 += __shfl_xor(s2,1);
    a += __shfl_xor(a,2);  s2 += __shfl_xor(s2,2);
    a += __shfl_xor(a,4);  s2 += __shfl_xor(s2,4);
    if(quad==0 && (m&7)==0){
      int g = nt*2 + (m>>3);
      atomicAdd(&stato[b*6+g], a);
      atomicAdd(&stato[24 + b*6+g], s2);
    }
  }
  // wave-internal LDS read (no barrier needed) -> 96B vector stores per voxel
  #pragma unroll
  for(int i=0;i<2;i++){
    int vid = lane*2 + i;
    int mm = vid>>3, par = vid&7;
    int vcm = vc0 + mm;
    int xh = vcm%24, yh = (vcm/24)%24, zh = vcm/576;
    int pz = par>>2, py = (par>>1)&1, px = par&1;
    size_t vout = (size_t)(2*zh+pz)*2304 + (2*yh+py)*48 + (2*xh+px);
    uint4x* dst = (uint4x*)(out + ((size_t)b*NVLL + vout)*48);
    const uint4x* srcl = (const uint4x*)&lds[wid][vid][0];
    #pragma unroll
    for(int q=0;q<6;q++) dst[q] = srcl[q];
  }
}

// ---------------- MFMA 1x1 conv: NHWC(48) or NCDHW-mix(32) in -> NHWC 48 out + GN stats
template<int CIN, bool MIX>
__global__ __launch_bounds__(256) void k_c1mm(const void* in, const bf16* __restrict__ wbf,
    const float* __restrict__ bias, bf16* out, float* __restrict__ stato, int set_out,
    const float* __restrict__ flag)
{
  constexpr int KT = (CIN+31)/32;
  const int f = MIX ? (int)flag[0] : 0;
  const int tid = threadIdx.x, wid = tid>>6, lane = tid&63;
  const int w = blockIdx.x*4 + wid;            // < 27648
  const size_t v0g = (size_t)w*16;
  const int b = (int)(v0g/NVLL);
  const size_t v0l = v0g - (size_t)b*NVLL;
  const int m = lane&15, quad = lane>>4;
  const short8x* wb8 = (const short8x*)wbf;
  const short8x zf = {0,0,0,0,0,0,0,0};

  short8x afh[KT], afl[MIX?KT:1];
  #pragma unroll
  for(int kt=0;kt<KT;kt++){
    if constexpr(MIX){
      short hh[8], ll[8];
      #pragma unroll
      for(int j=0;j<8;j++){
        int ch = kt*32 + quad*8 + j;
        float v = ldmix(in, ((size_t)(b*CIN+ch))*NVLL + v0l + m, f);
        bf16 h = __float2bfloat16(v);
        float hf = __bfloat162float(h);
        bf16 l = __float2bfloat16(v - hf);
        __builtin_memcpy(&hh[j], &h, 2); __builtin_memcpy(&ll[j], &l, 2);
      }
      __builtin_memcpy(&afh[kt], hh, 16); __builtin_memcpy(&afl[kt], ll, 16);
    } else {
      int k0 = kt*32 + quad*8;
      short8x a = *(const short8x*)((const bf16*)in + (v0g + m)*48 + k0);
      afh[kt] = (k0 < CIN) ? a : zf;
    }
  }

  f32x4 acc[3];
  #pragma unroll
  for(int nt=0;nt<3;nt++) acc[nt] = (f32x4){0.f,0.f,0.f,0.f};
  #pragma unroll
  for(int kt=0;kt<KT;kt++){
    #pragma unroll
    for(int nt=0;nt<3;nt++){
      short8x bfr = wb8[(size_t)(kt*3+nt)*64 + lane];
      acc[nt] = __builtin_amdgcn_mfma_f32_16x16x32_bf16(afh[kt], bfr, acc[nt], 0,0,0);
      if constexpr(MIX)
        acc[nt] = __builtin_amdgcn_mfma_f32_16x16x32_bf16(afl[kt], bfr, acc[nt], 0,0,0);
    }
  }

  __shared__ bf16 lds[4][16][48];
  float sl[3] = {0,0,0}, ssl[3] = {0,0,0};
  #pragma unroll
  for(int nt=0;nt<3;nt++){
    int oc = nt*16 + m;
    float bv = bias[oc];
    #pragma unroll
    for(int r=0;r<4;r++){
      float v = acc[nt][r] + bv;
      lds[wid][quad*4+r][oc] = __float2bfloat16(v);
      sl[nt] += v; ssl[nt] += v*v;
    }
  }
  #pragma unroll
  for(int nt=0;nt<3;nt++){
    float a = sl[nt], s2 = ssl[nt];
    a += __shfl_xor(a,16); s2 += __shfl_xor(s2,16);
    a += __shfl_xor(a,32); s2 += __shfl_xor(s2,32);
    a += __shfl_xor(a,1);  s2 += __shfl_xor(s2,1);
    a += __shfl_xor(a,2);  s2 += __shfl_xor(s2,2);
    a += __shfl_xor(a,4);  s2 += __shfl_xor(s2,4);
    if(quad==0 && (m&7)==0){
      int g = nt*2 + (m>>3);
      atomicAdd(&stato[set_out*48 + b*6+g], a);
      atomicAdd(&stato[set_out*48 + 24 + b*6+g], s2);
    }
  }
  if(lane < 16){
    uint4x* dst = (uint4x*)(out + (v0g + lane)*48);
    const uint4x* srcl = (const uint4x*)&lds[wid][lane][0];
    #pragma unroll
    for(int q=0;q<6;q++) dst[q] = srcl[q];
  }
}

// ---------------- GN apply + leaky(0.1), NHWC vectorized ----------------
__global__ __launch_bounds__(256) void k_gn_apply(bf16* buf, const float* __restrict__ stats, int set,
    const float* __restrict__ gamma, const float* __restrict__ beta)
{
  const int v = blockIdx.x*256 + threadIdx.x;
  const int b = blockIdx.y;
  const float invN = 1.0f/(8.0f*(float)NV);
  float m[6], rs[6];
  #pragma unroll
  for(int g=0;g<6;g++){
    float s  = stats[set*48 + b*6+g];
    float ss = stats[set*48 + 24 + b*6+g];
    float mm = s*invN; float var = ss*invN - mm*mm;
    m[g] = mm; rs[g] = rsqrtf(var + 1e-5f);
  }
  uint4x* p4 = (uint4x*)(buf + ((size_t)b*NVLL + v)*48);
  uint4x w6[6];
  #pragma unroll
  for(int q=0;q<6;q++) w6[q] = p4[q];
  unsigned int* wu = (unsigned int*)w6;
  #pragma unroll
  for(int c2=0;c2<24;c2++){
    int c0 = 2*c2;
    float x0 = lo2f(wu[c2]), x1 = hi2f(wu[c2]);
    int g0 = c0>>3, g1 = (c0+1)>>3;
    x0 = (x0 - m[g0])*rs[g0]*gamma[c0] + beta[c0];
    x1 = (x1 - m[g1])*rs[g1]*gamma[c0+1] + beta[c0+1];
    x0 = x0 < 0.f ? 0.1f*x0 : x0;
    x1 = x1 < 0.f ? 0.1f*x1 : x1;
    wu[c2] = pk2(x0, x1);
  }
  #pragma unroll
  for(int q=0;q<6;q++) p4[q] = w6[q];
}

// ---------------- pool 48^3 -> 6^3 (vectorized NHWC loads) ----------------
__global__ __launch_bounds__(512) void k_pool2(const bf16* __restrict__ s0, const bf16* __restrict__ s1,
    float* __restrict__ d0, float* __restrict__ d1)
{
  const int which = blockIdx.y;
  const bf16* src = which ? s1 : s0;
  float*      dst = which ? d1 : d0;
  const int cell = blockIdx.x % 216, b = blockIdx.x/216;
  const int tid = threadIdx.x;
  const int cz=cell/36, cy=(cell/6)%6, cx=cell%6;
  const int dz=tid>>6, dy=(tid>>3)&7, dx=tid&7;
  const size_t vox = (size_t)(cz*8+dz)*2304 + (cy*8+dy)*48 + (cx*8+dx);
  const uint4x* p4 = (const uint4x*)(src + ((size_t)b*NVLL + vox)*48);
  uint4x w6[6];
  #pragma unroll
  for(int q=0;q<6;q++) w6[q] = p4[q];
  const unsigned int* wu = (const unsigned int*)w6;
  float val[48];
  #pragma unroll
  for(int c2=0;c2<24;c2++){ val[2*c2] = lo2f(wu[c2]); val[2*c2+1] = hi2f(wu[c2]); }
  __shared__ float rmax[8][48], rsum[8][48];
  const int wid=tid>>6, lane=tid&63;
  #pragma unroll
  for(int o=0;o<48;o++){
    float mx=val[o], sm=val[o];
    #pragma unroll
    for(int s=32;s>=1;s>>=1){ mx=fmaxf(mx,__shfl_xor(mx,s)); sm+=__shfl_xor(sm,s); }
    if(lane==0){ rmax[wid][o]=mx; rsum[wid][o]=sm; }
  }
  __syncthreads();
  if(tid<48){
    float mx=rmax[0][tid], sm=rsum[0][tid];
    #pragma unroll
    for(int w2=1;w2<8;w2++){ mx=fmaxf(mx,rmax[w2][tid]); sm+=rsum[w2][tid]; }
    dst[(size_t)(b*48+tid)*216 + cell] = mx + sm*(1.f/512.f);
  }
}

// ---------------- fused conv1x1(concat(xe, folded-x0)) + pool -> pkv -------------------
__global__ __launch_bounds__(512) void k_poolfuse(const void* __restrict__ xe, const void* __restrict__ x,
    const float* __restrict__ W, float* __restrict__ pkv, const float* __restrict__ flag)
{
  const int f = (int)flag[0];
  const int cell = blockIdx.x % 216;
  const int b = blockIdx.x / 216;
  const int tid = threadIdx.x;
  const int cz = cell/36, cy = (cell/6)%6, cx = cell%6;
  const int dz = tid>>6, dy = (tid>>3)&7, dx = tid&7;
  const int gz = cz*8+dz, gy = cy*8+dy, gx = cx*8+dx;
  const size_t voff = (size_t)gz*2304 + gy*48 + gx;
  const int par = ((gz&1)<<2) | ((gy&1)<<1) | (gx&1);
  const int vh = (gz>>1)*576 + (gy>>1)*24 + (gx>>1);
  float xev[32], xrv[64];
  #pragma unroll
  for(int c=0;c<32;c++) xev[c] = ldmix(xe, ((size_t)(b*32+c))*NVLL + voff, f);
  #pragma unroll
  for(int c=0;c<64;c++) xrv[c] = ldmix(x, (size_t)(b*64+c)*13824 + vh, f);
  const float* wf  = W + W_WF;
  const float* wfp = W + W_WFP + par*3072;
  const float* bff = W + W_BFF;
  __shared__ float rmax[8][48];
  __shared__ float rsum[8][48];
  const int wid = tid>>6, lane = tid&63;
  #pragma unroll
  for(int o=0;o<48;o++){
    float acc = bff[o];
    #pragma unroll
    for(int c=0;c<32;c++) acc += wf[o*64+c]*xev[c];
    #pragma unroll
    for(int c=0;c<64;c++) acc += wfp[o*64+c]*xrv[c];
    float mx = acc, sm = acc;
    #pragma unroll
    for(int s=32;s>=1;s>>=1){ mx = fmaxf(mx, __shfl_xor(mx,s)); sm += __shfl_xor(sm,s); }
    if(lane==0){ rmax[wid][o] = mx; rsum[wid][o] = sm; }
  }
  __syncthreads();
  if(tid < 48){
    float mx = rmax[0][tid], sm = rsum[0][tid];
    #pragma unroll
    for(int w2=1;w2<8;w2++){ mx = fmaxf(mx, rmax[w2][tid]); sm += rsum[w2][tid]; }
    pkv[((size_t)(b*48+tid))*216 + cell] = mx + sm*(1.f/512.f);
  }
}

// ---------------- linear cross-attention ----------------
__global__ __launch_bounds__(256) void k_attn(const float* __restrict__ p1, const float* __restrict__ p2,
    const float* __restrict__ pkv, const float* __restrict__ W, float* __restrict__ a1, float* __restrict__ a2)
{
  const int which = blockIdx.x, b = blockIdx.y;
  const float* wb = W + W_ATT + which*9408;
  const float* wq = wb;        const float* bq = wb+2304;
  const float* wk = wb+2352;   const float* bk = wb+4656;
  const float* wv = wb+4704;   const float* bv = wb+7008;
  const float* wo = wb+7056;   const float* bo = wb+9360;
  const float* q   = which ? p2 : p1;
  float*       aout= which ? a2 : a1;
  const float* kvb = pkv + (size_t)b*48*216;
  const float* qb  = q   + (size_t)b*48*216;
  __shared__ float kh[216*48];
  __shared__ float ctx[288];
  const int tid = threadIdx.x;

  if(tid < 216){
    float kvr[48];
    #pragma unroll
    for(int c=0;c<48;c++) kvr[c] = kvb[c*216 + tid];
    #pragma unroll
    for(int o=0;o<48;o++){
      float acc = bk[o];
      #pragma unroll
      for(int c=0;c<48;c++) acc += kvr[c]*wk[o*48+c];
      kh[tid*48+o] = acc;
    }
  }
  __syncthreads();
  if(tid < 48){
    float mx = -1e30f;
    for(int n=0;n<216;n++) mx = fmaxf(mx, kh[n*48+tid]);
    float s = 0.f;
    for(int n=0;n<216;n++){ float e = __expf(kh[n*48+tid]-mx); kh[n*48+tid] = e; s += e; }
    float inv = 1.f/s;
    for(int n=0;n<216;n++) kh[n*48+tid] *= inv;
  }
  __syncthreads();
  if(tid < 48){
    int h = tid/6, e = tid%6;
    float cacc[6] = {0,0,0,0,0,0};
    for(int n=0;n<216;n++){
      float vh = bv[h*6+e];
      #pragma unroll
      for(int c=0;c<48;c++) vh += kvb[c*216+n]*wv[(h*6+e)*48+c];
      #pragma unroll
      for(int d=0;d<6;d++) cacc[d] += kh[n*48 + h*6+d]*vh;
    }
    #pragma unroll
    for(int d=0;d<6;d++) ctx[(h*6+d)*6+e] = cacc[d];
  }
  __syncthreads();
  if(tid < 216){
    int n = tid;
    float qr[48];
    #pragma unroll
    for(int c=0;c<48;c++) qr[c] = qb[c*216 + n];
    float qh[48];
    #pragma unroll
    for(int o=0;o<48;o++){
      float acc = bq[o];
      #pragma unroll
      for(int c=0;c<48;c++) acc += qr[c]*wq[o*48+c];
      qh[o] = acc;
    }
    #pragma unroll
    for(int h=0;h<8;h++){
      float mx = qh[h*6];
      #pragma unroll
      for(int d=1;d<6;d++) mx = fmaxf(mx, qh[h*6+d]);
      float s = 0.f;
      #pragma unroll
      for(int d=0;d<6;d++){ float e = __expf(qh[h*6+d]-mx); qh[h*6+d] = e; s += e; }
      float inv = 1.f/s;
      #pragma unroll
      for(int d=0;d<6;d++) qh[h*6+d] *= inv;
    }
    float ov[48];
    #pragma unroll
    for(int h=0;h<8;h++){
      #pragma unroll
      for(int e=0;e<6;e++){
        float acc = 0.f;
        #pragma unroll
        for(int d=0;d<6;d++) acc += qh[h*6+d]*ctx[(h*6+d)*6+e];
        ov[h*6+e] = acc;
      }
    }
    #pragma unroll
    for(int o=0;o<48;o++){
      float acc = bo[o];
      #pragma unroll
      for(int c=0;c<48;c++) acc += ov[c]*wo[o*48+c];
      aout[((size_t)(b*48+o))*216 + n] = acc;
    }
  }
}

// ---------------- gate: i1 *= sig(up(a1)), i2 *= sig(up(a2)), vectorized ----------------
__device__ inline void interp1(int u, int& i0, int& i1, float& t){
  float pos = u * (5.0f/47.0f);
  float f = floorf(pos);
  i0 = (int)f; if(i0 > 5) i0 = 5;
  i1 = i0+1 > 5 ? 5 : i0+1;
  t = pos - f; if(t < 0.f) t = 0.f; if(t > 1.f) t = 1.f;
}

__global__ __launch_bounds__(256) void k_gate(bf16* i1b, bf16* i2b,
    const float* __restrict__ a1, const float* __restrict__ a2)
{
  const int v = blockIdx.x*256 + threadIdx.x;
  const int b = blockIdx.y;
  const int x = v % 48, y = (v/48) % 48, z = v/2304;
  int xi0,xi1,yi0,yi1,zi0,zi1; float xt,yt,zt;
  interp1(x,xi0,xi1,xt); interp1(y,yi0,yi1,yt); interp1(z,zi0,zi1,zt);
  int off[8]; float cw[8];
  off[0]=zi0*36+yi0*6+xi0; cw[0]=(1-zt)*(1-yt)*(1-xt);
  off[1]=zi0*36+yi0*6+xi1; cw[1]=(1-zt)*(1-yt)*xt;
  off[2]=zi0*36+yi1*6+xi0; cw[2]=(1-zt)*yt*(1-xt);
  off[3]=zi0*36+yi1*6+xi1; cw[3]=(1-zt)*yt*xt;
  off[4]=zi1*36+yi0*6+xi0; cw[4]=zt*(1-yt)*(1-xt);
  off[5]=zi1*36+yi0*6+xi1; cw[5]=zt*(1-yt)*xt;
  off[6]=zi1*36+yi1*6+xi0; cw[6]=zt*yt*(1-xt);
  off[7]=zi1*36+yi1*6+xi1; cw[7]=zt*yt*xt;
  const float* A1b = a1 + (size_t)b*48*216;
  const float* A2b = a2 + (size_t)b*48*216;

  uint4x* p14 = (uint4x*)(i1b + ((size_t)b*NVLL + v)*48);
  uint4x* p24 = (uint4x*)(i2b + ((size_t)b*NVLL + v)*48);
  uint4x w6[6];
  #pragma unroll
  for(int q=0;q<6;q++) w6[q] = p14[q];
  unsigned int* wu = (unsigned int*)w6;
  #pragma unroll
  for(int c2=0;c2<24;c2++){
    int c0 = 2*c2;
    float s0 = 0.f, s1 = 0.f;
    #pragma unroll
    for(int k=0;k<8;k++){ s0 += cw[k]*A1b[c0*216+off[k]]; s1 += cw[k]*A1b[(c0+1)*216+off[k]]; }
    s0 = 1.f/(1.f + __expf(-s0));
    s1 = 1.f/(1.f + __expf(-s1));
    wu[c2] = pk2(s0*lo2f(wu[c2]), s1*hi2f(wu[c2]));
  }
  #pragma unroll
  for(int q=0;q<6;q++) p14[q] = w6[q];

  #pragma unroll
  for(int q=0;q<6;q++) w6[q] = p24[q];
  #pragma unroll
  for(int c2=0;c2<24;c2++){
    int c0 = 2*c2;
    float s0 = 0.f, s1 = 0.f;
    #pragma unroll
    for(int k=0;k<8;k++){ s0 += cw[k]*A2b[c0*216+off[k]]; s1 += cw[k]*A2b[(c0+1)*216+off[k]]; }
    s0 = 1.f/(1.f + __expf(-s0));
    s1 = 1.f/(1.f + __expf(-s1));
    wu[c2] = pk2(s0*lo2f(wu[c2]), s1*hi2f(wu[c2]));
  }
  #pragma unroll
  for(int q=0;q<6;q++) p24[q] = w6[q];
}

// ---------------- MFMA implicit-GEMM 3x3x3 conv (unchanged) ----------------
template<int KT, bool TWO, bool USETB>
__global__ __launch_bounds__(256) void k_conv3m(
    const bf16* __restrict__ in0, const bf16* __restrict__ in1,
    const bf16* __restrict__ wb, const float* __restrict__ tb, const float* __restrict__ cb,
    bf16* __restrict__ outp, float* __restrict__ stato, int sOut, int bidx, int onhwc)
{
  const int tid = threadIdx.x;
  const int wid = tid>>6, lane = tid&63;
  const int run = blockIdx.x*4 + wid;          // 6912 runs
  const int x0 = (run%3)*16, y = (run/3)%48, z = run/144;
  const int m = lane&15, quad = lane>>4;
  const int CB = TWO ? 48 : 32;
  const int k0 = quad*8;
  const short8x* wb8 = (const short8x*)wb;
  const short8x zf = {0,0,0,0,0,0,0,0};

  f32x4 acc0 = {0.f,0.f,0.f,0.f};
  f32x4 acc1 = {0.f,0.f,0.f,0.f};

  for(int dz=0; dz<3; dz++){
    int zz = z + dz - 1;
    if(zz < 0 || zz >= 48) continue;
    for(int dy=0; dy<3; dy++){
      int yy = y + dy - 1;
      if(yy < 0 || yy >= 48) continue;
      #pragma unroll
      for(int dx=0; dx<3; dx++){
        int xx = x0 + m + dx - 1;
        bool ok = (xx >= 0 && xx < 48);
        int xc = xx < 0 ? 0 : (xx > 47 ? 47 : xx);
        int vox = zz*2304 + yy*48 + xc;
        int tap = dz*9 + dy*3 + dx;
        #pragma unroll
        for(int kt=0; kt<KT; kt++){
          int kk = kt*32 + k0;
          const bf16* src; int ch;
          if(TWO){ if(kk < 48){ src = in0; ch = kk; } else { src = in1; ch = kk-48; } }
          else    { src = in0; ch = kk; }
          short8x af = *(const short8x*)(src + (size_t)vox*CB + ch);
          if(!ok) af = zf;
          short8x b0 = wb8[ (size_t)((tap*KT + kt)*2 + 0)*64 + lane ];
          short8x b1 = wb8[ (size_t)((tap*KT + kt)*2 + 1)*64 + lane ];
          acc0 = __builtin_amdgcn_mfma_f32_16x16x32_bf16(af, b0, acc0, 0,0,0);
          acc1 = __builtin_amdgcn_mfma_f32_16x16x32_bf16(af, b1, acc1, 0,0,0);
        }
      }
    }
  }

  const int oc0 = m, oc1 = 16 + m;
  float s0=0.f, ss0=0.f, s1=0.f, ss1=0.f;
  #pragma unroll
  for(int r=0;r<4;r++){
    int mv = quad*4 + r;
    int xr = x0 + mv;
    float b0v = cb[oc0], b1v = cb[oc1];
    if constexpr(USETB){
      #pragma unroll
      for(int t=0;t<27;t++){
        int tdz = t/9, tdy = (t/3)%3, tdx = t%3;
        int zz = z+tdz-1, yy = y+tdy-1, xx = xr+tdx-1;
        if(zz>=0 && zz<48 && yy>=0 && yy<48 && xx>=0 && xx<48){
          b0v += tb[t*32+oc0]; b1v += tb[t*32+oc1];
        }
      }
    }
    float v0 = acc0[r] + b0v;
    float v1 = acc1[r] + b1v;
    size_t vox = (size_t)z*2304 + y*48 + xr;
    if(onhwc){
      outp[vox*32 + oc0] = __float2bfloat16(v0);
      outp[vox*32 + oc1] = __float2bfloat16(v1);
    } else {
      outp[(size_t)oc0*NVLL + vox] = __float2bfloat16(v0);
      outp[(size_t)oc1*NVLL + vox] = __float2bfloat16(v1);
    }
    s0 += v0; ss0 += v0*v0; s1 += v1; ss1 += v1*v1;
  }
  s0 += __shfl_xor(s0,16); ss0 += __shfl_xor(ss0,16); s1 += __shfl_xor(s1,16); ss1 += __shfl_xor(ss1,16);
  s0 += __shfl_xor(s0,32); ss0 += __shfl_xor(ss0,32); s1 += __shfl_xor(s1,32); ss1 += __shfl_xor(ss1,32);
  if(quad==0){
    atomicAdd(&stato[sOut + bidx*32 + oc0], s0);
    atomicAdd(&stato[sOut + 128 + bidx*32 + oc0], ss0);
    atomicAdd(&stato[sOut + bidx*32 + oc1], s1);
    atomicAdd(&stato[sOut + 128 + bidx*32 + oc1], ss1);
  }
}

// ---------------- IN + leaky(0.01) on h1 (NHWC) ----------------
struct P4 { bf16* p[4]; };
__global__ __launch_bounds__(256) void k_inleak(P4 h1, const float* __restrict__ stats){
  int gid = blockIdx.x*256 + threadIdx.x;      // grid 1728: thread per voxel
  int b = gid/NV; int v = gid - b*NV;
  const float invN = 1.f/(float)NV;
  uint4x* p4 = (uint4x*)(h1.p[b] + (size_t)v*32);
  uint4x w4[4];
  #pragma unroll
  for(int q=0;q<4;q++) w4[q] = p4[q];
  unsigned int* wu = (unsigned int*)w4;
  #pragma unroll
  for(int c2=0;c2<16;c2++){
    int c0 = 2*c2;
    float s0  = stats[192 + b*32 + c0];
    float ss0 = stats[192 + 128 + b*32 + c0];
    float s1  = stats[192 + b*32 + c0+1];
    float ss1 = stats[192 + 128 + b*32 + c0+1];
    float m0 = s0*invN, m1 = s1*invN;
    float r0 = rsqrtf(ss0*invN - m0*m0 + 1e-5f);
    float r1 = rsqrtf(ss1*invN - m1*m1 + 1e-5f);
    float x0 = (lo2f(wu[c2]) - m0)*r0;
    float x1 = (hi2f(wu[c2]) - m1)*r1;
    x0 = x0 < 0.f ? 0.01f*x0 : x0;
    x1 = x1 < 0.f ? 0.01f*x1 : x1;
    wu[c2] = pk2(x0, x1);
  }
  #pragma unroll
  for(int q=0;q<4;q++) p4[q] = w4[q];
}

// ---------------- final IN + leaky(0.01): h2 slabs (NCHW) -> d_out, x8 vector ----------
__global__ __launch_bounds__(256) void k_in_final(P4 h2, const float* __restrict__ stats,
    void* out, const float* __restrict__ flag)
{
  const int f = (int)flag[0];
  int gid = blockIdx.x*256 + threadIdx.x;      // grid 6912 blocks, 8 elem/thread
  size_t i8 = (size_t)gid*8;
  int b = (int)(i8/(NV*32)); int j = (int)(i8 - (size_t)b*(NV*32));
  int c = j/NV;
  const float invN = 1.f/(float)NV;
  float s  = stats[448 + b*32 + c];
  float ss = stats[448 + 128 + b*32 + c];
  float m = s*invN; float var = ss*invN - m*m; float rs = rsqrtf(var + 1e-5f);
  uint4x w = *(uint4x*)(h2.p[b] + j);
  const unsigned int* wu = (const unsigned int*)&w;
  float vv[8];
  #pragma unroll
  for(int k2=0;k2<4;k2++){ vv[2*k2] = lo2f(wu[k2]); vv[2*k2+1] = hi2f(wu[k2]); }
  #pragma unroll
  for(int k=0;k<8;k++){
    float xv = (vv[k]-m)*rs;
    vv[k] = xv < 0.f ? 0.01f*xv : xv;
  }
  if(f){
    float* op = (float*)out + i8;
    uint4x o0, o1;
    __builtin_memcpy(&o0, &vv[0], 16);
    __builtin_memcpy(&o1, &vv[4], 16);
    ((uint4x*)op)[0] = o0; ((uint4x*)op)[1] = o1;
  } else {
    unsigned int pk[4];
    #pragma unroll
    for(int k2=0;k2<4;k2++) pk[k2] = pk2(vv[2*k2], vv[2*k2+1]);
    *(uint4x*)((bf16*)out + i8) = *(uint4x*)pk;
  }
}

// ==========================================================================
extern "C" void kernel_launch(void* const* d_in, const int* in_sizes, int n_in,
                              void* d_out, int out_size, void* d_ws, size_t ws_size,
                              hipStream_t stream)
{
  (void)in_sizes; (void)n_in; (void)out_size; (void)ws_size;
  char* base = (char*)d_ws;
  const void* x  = d_in[0];
  const void* xe = d_in[1];

  float* SM  = (float*)base;
  float* P1  = SM + SM_P1;
  float* P2  = SM + SM_P2;
  float* PKV = SM + SM_PKV;
  float* A1  = SM + SM_A1;
  float* A2  = SM + SM_A2;
  float* ST  = SM + SM_ST;
  float* W   = SM + SM_W;
  float* FL  = SM + SM_FL;
  bf16*  O1  = (bf16*)(base + BOFF_O1);
  bf16*  O2  = (bf16*)(base + BOFF_O2);

  P4 H1, H2;
  H1.p[0] = (bf16*)(base + BOFF_SP);
  H1.p[1] = (bf16*)(base + BOFF_O1);
  H1.p[2] = (bf16*)(base + BOFF_O1 + SLOT48);
  H1.p[3] = (bf16*)(base + BOFF_O1 + 2*SLOT48);
  for(int b=0;b<4;b++) H2.p[b] = (bf16*)(base + BOFF_O2 + (size_t)b*SLOT48);

  k_detect<<<1, 256, 0, stream>>>(xe, FL);
  k_zero<<<3, 256, 0, stream>>>(ST);

  PtrTab pt;
  for(int i=0;i<36;i++) pt.p[i] = d_in[i+2];
  k_prep<<<(W_TOTAL+255)/256, 256, 0, stream>>>(pt, W, FL);
  k_fold <<<193, 256, 0, stream>>>(W);
  k_fold2<<<328, 256, 0, stream>>>(W);
  k_packb1<<<324, 256, 0, stream>>>(W);
  k_packb2<<<108, 256, 0, stream>>>(W);
  k_packc<<<6,  256, 0, stream>>>(W, W_W2, 32, 1, W_WB3);
  k_packc<<<12, 256, 0, stream>>>(W, W_W3, 48, 2, W_WB4);
  k_packc<<<12, 256, 0, stream>>>(W, W_W4, 48, 2, W_WB5);
  k_packi1<<<96, 256, 0, stream>>>(W);

  const float* gam = W + W_GNG;
  const float* bet = W + W_GNB;

  // i1 branch -> O1 (NHWC): MFMA deconv+w1, GN(0), MFMA w3, GN(1)
  k_i1mm<<<864, 256, 0, stream>>>(x, W, O1, ST, FL);
  k_gn_apply<<<dim3(432,4), 256, 0, stream>>>(O1, ST, 0, gam, bet);
  k_c1mm<48,false><<<6912, 256, 0, stream>>>(O1, (const bf16*)(W+W_WB4), W+W_B3, O1, ST, 1, FL);
  k_gn_apply<<<dim3(432,4), 256, 0, stream>>>(O1, ST, 1, gam, bet);

  // i2 branch -> O2 (NHWC): MFMA w2 (mix), GN(2), MFMA w4, GN(3)
  k_c1mm<32,true ><<<6912, 256, 0, stream>>>(xe, (const bf16*)(W+W_WB3), W+W_B2, O2, ST, 2, FL);
  k_gn_apply<<<dim3(432,4), 256, 0, stream>>>(O2, ST, 2, gam, bet);
  k_c1mm<48,false><<<6912, 256, 0, stream>>>(O2, (const bf16*)(W+W_WB5), W+W_B4, O2, ST, 3, FL);
  k_gn_apply<<<dim3(432,4), 256, 0, stream>>>(O2, ST, 3, gam, bet);

  // pools + attention
  k_pool2<<<dim3(864,2), 512, 0, stream>>>(O1, O2, P1, P2);
  k_poolfuse<<<864, 512, 0, stream>>>(xe, x, W, PKV, FL);
  k_attn<<<dim3(2,4), 256, 0, stream>>>(P1, P2, PKV, W, A1, A2);

  // gate i1,i2 in place -> o1,o2
  k_gate<<<dim3(432,4), 256, 0, stream>>>(O1, O2, A1, A2);

  // conv#1 (folded with Wfin): 96ch NHWC -> h1 (NHWC 32ch), IN stats @192
  for(int b=0;b<4;b++){
    const bf16* o1b = O1 + (size_t)b*48*NVLL;
    const bf16* o2b = O2 + (size_t)b*48*NVLL;
    k_conv3m<3,true,true><<<1728, 256, 0, stream>>>(o1b, o2b, (const bf16*)(W+W_WB1), W+W_TB, W+W_C0B,
                                                    H1.p[b], ST, 192, b, 1);
  }
  k_inleak<<<1728, 256, 0, stream>>>(H1, ST);

  // conv#2: 32ch NHWC -> h2 (NCHW slab), IN stats @448
  for(int b=0;b<4;b++){
    k_conv3m<1,false,false><<<1728, 256, 0, stream>>>(H1.p[b], nullptr, (const bf16*)(W+W_WB2), nullptr, W+W_C1B,
                                                      H2.p[b], ST, 448, b, 0);
  }
  k_in_final<<<6912, 256, 0, stream>>>(H2, ST, d_out, FL);
}

// Round 8
// 1816.911 us; speedup vs baseline: 2.9352x; 2.9352x over previous
//
#include <hip/hip_runtime.h>
#include <hip/hip_bf16.h>

typedef __hip_bfloat16 bf16;
typedef __attribute__((ext_vector_type(8))) short short8x;
typedef __attribute__((ext_vector_type(4))) float f32x4;
typedef __attribute__((ext_vector_type(4))) unsigned int uint4x;

#define NV 110592           // 48^3
#define NVLL 110592ull
#define NSH 64              // stats shards
#define STSTRIDE 704

__device__ inline float ldmix(const void* p, size_t i, int f){
  return f ? ((const float*)p)[i] : __bfloat162float(((const bf16*)p)[i]);
}
__device__ inline float lo2f(unsigned int u){ union{unsigned int i; float f;} t; t.i = u<<16; return t.f; }
__device__ inline float hi2f(unsigned int u){ union{unsigned int i; float f;} t; t.i = u & 0xffff0000u; return t.f; }
__device__ inline unsigned short bfb(float f){ bf16 h=__float2bfloat16(f); unsigned short u; __builtin_memcpy(&u,&h,2); return u; }
__device__ inline unsigned int pk2(float a, float b){ return (unsigned int)bfb(a) | ((unsigned int)bfb(b)<<16); }

// ---------------- workspace layout (BYTES), total <= 96 MiB ----------------
static const size_t BOFF_O1 = 2621440;
static const size_t BOFF_O2 = 45088768;
static const size_t BOFF_SP = 87556096;
static const size_t SLOT48  = 10616832;
// small-region float offsets
#define SM_P1   0
#define SM_P2   41472
#define SM_PKV  82944
#define SM_A1   124416
#define SM_A2   165888
#define SM_ST   207360   // 64 shards x 704 floats = 45056
#define SM_W    252416

// fp32 weight region offsets (floats, relative to W)
#define W_UPW   0
#define W_UPB   16384
#define W_WF    16416
#define W_BF    19488
#define W_W1    19536
#define W_B1    21072
#define W_W2    21120
#define W_B2    22656
#define W_W3    22704
#define W_B3    25008
#define W_W4    25056
#define W_B4    27360
#define W_GNG   27408
#define W_GNB   27456
#define W_ATT   27504
#define W_WFIN  46320
#define W_BFIN  52464
#define W_C0W   52528
#define W_C0B   107824
#define W_C1W   107856
#define W_C1B   135504
#define W_TOTAL 135536
#define W_W1P   135536   // [8][48][64]
#define W_B1F   160112
#define W_WFP   160160   // [8][48][64]
#define W_BFF   184736
#define W_WP    184784   // fp32 [32 oc][96 k][27 tap]
#define W_TB    267728   // fp32 [27 tap][32 oc]
#define W_WB1   268592   // bf16[82944]  conv3 #1 frags
#define W_WB2   310064   // bf16[27648]  conv3 #2 frags
#define W_WB3   323888   // bf16[1536]   W2 frags (K=32)
#define W_WB4   324656   // bf16[3072]   W3 frags (K=48 padded)
#define W_WB5   326192   // bf16[3072]   W4 frags (K=48 padded)
#define W_WBI   327728   // bf16[24576]  W1P frags [8 par][2 kt][3 nt]
#define SM_FL   604720

// ---------------- dtype detect ----------------
__global__ __launch_bounds__(256) void k_detect(const void* xe, float* __restrict__ flag){
  const bf16* p = (const bf16*)xe;
  int tid = threadIdx.x;
  float mx = 0.f;
  for(int i=tid;i<8192;i+=256){
    float v = fabsf(__bfloat162float(p[i]));
    if(!(v==v)) v = 1e30f;
    mx = fmaxf(mx, v);
  }
  #pragma unroll
  for(int s=32;s>=1;s>>=1) mx = fmaxf(mx, __shfl_xor(mx,s));
  __shared__ float red[4];
  if((tid&63)==0) red[tid>>6] = mx;
  __syncthreads();
  if(tid==0){
    float m = fmaxf(fmaxf(red[0],red[1]), fmaxf(red[2],red[3]));
    flag[0] = (m > 1e3f) ? 1.f : 0.f;
  }
}

__global__ __launch_bounds__(256) void k_zero(float* __restrict__ st){
  int i = blockIdx.x*256 + threadIdx.x;
  if(i < NSH*STSTRIDE) st[i] = 0.f;
}

// ---------------- weight prep ----------------
struct PtrTab { const void* p[36]; };
__device__ const int g_seg[36] = {16384,32,3072,48,1536,48,1536,48,2304,48,2304,48,48,48,
  2304,48,2304,48,2304,48,2304,48,2304,48,2304,48,2304,48,2304,48,6144,64,55296,32,27648,32};

__global__ __launch_bounds__(256) void k_prep(PtrTab t, float* __restrict__ W, const float* __restrict__ flag){
  const int f = (int)flag[0];
  int i = blockIdx.x*256 + threadIdx.x;
  if(i >= W_TOTAL) return;
  int rem = i;
  for(int s=0;s<36;s++){
    int sz = g_seg[s];
    if(rem < sz){ W[i] = ldmix(t.p[s], rem, f); return; }
    rem -= sz;
  }
}

__global__ __launch_bounds__(256) void k_fold(float* __restrict__ W){
  int i = blockIdx.x*256 + threadIdx.x;
  const float* upw = W + W_UPW;
  const float* upb = W + W_UPB;
  if(i < 49152){
    int which = i / 24576;
    int r = i % 24576;
    int par = r / 3072; int o = (r/64)%48; int c = r%64;
    float acc = 0.f;
    for(int m=0;m<32;m++){
      float wm = which ? W[W_WF + o*64 + 32 + m] : W[W_W1 + o*32 + m];
      acc += wm * upw[c*256 + m*8 + par];
    }
    W[(which ? W_WFP : W_W1P) + par*3072 + o*64 + c] = acc;
  } else if(i < 49248){
    int j = i - 49152;
    int which = j / 48; int o = j % 48;
    float acc = which ? W[W_BF + o] : W[W_B1 + o];
    for(int m=0;m<32;m++){
      float wm = which ? W[W_WF + o*64 + 32 + m] : W[W_W1 + o*32 + m];
      acc += wm * upb[m];
    }
    W[(which ? W_BFF : W_B1F) + o] = acc;
  }
}

__global__ __launch_bounds__(256) void k_fold2(float* __restrict__ W){
  int i = blockIdx.x*256 + threadIdx.x;
  if(i < 82944){
    int tap = i%27; int k = (i/27)%96; int oc = i/(27*96);
    float acc = 0.f;
    for(int m=0;m<64;m++) acc += W[W_C0W + oc*1728 + m*27 + tap] * W[W_WFIN + m*96 + k];
    W[W_WP + i] = acc;
  } else if(i < 83808){
    int j = i - 82944;
    int tap = j/32, oc = j%32;
    float acc = 0.f;
    for(int m=0;m<64;m++) acc += W[W_C0W + oc*1728 + m*27 + tap] * W[W_BFIN + m];
    W[W_TB + tap*32 + oc] = acc;
  }
}

__global__ __launch_bounds__(256) void k_packb1(float* __restrict__ W){
  int i = blockIdx.x*256 + threadIdx.x;
  if(i >= 82944) return;
  int j = i&7; int lane = (i>>3)&63; int frag = i>>9;
  int nt = frag&1; int tkt = frag>>1; int kt = tkt%3; int tap = tkt/3;
  int oc = nt*16 + (lane&15);
  int k  = kt*32 + ((lane>>4)<<3) + j;
  ((bf16*)(W + W_WB1))[i] = __float2bfloat16(W[W_WP + oc*2592 + k*27 + tap]);
}
__global__ __launch_bounds__(256) void k_packb2(float* __restrict__ W){
  int i = blockIdx.x*256 + threadIdx.x;
  if(i >= 27648) return;
  int j = i&7; int lane = (i>>3)&63; int frag = i>>9;
  int nt = frag&1; int tap = frag>>1;
  int oc = nt*16 + (lane&15);
  int ic = ((lane>>4)<<3) + j;
  ((bf16*)(W + W_WB2))[i] = __float2bfloat16(W[W_C1W + oc*864 + ic*27 + tap]);
}

// pack generic 1x1 weights [48][cin] -> B frags [kt][nt][lane][8], K zero-padded
__global__ __launch_bounds__(256) void k_packc(float* __restrict__ W, int srcoff, int cin, int ktc, int dstoff){
  int i = blockIdx.x*256 + threadIdx.x;
  if(i >= ktc*1536) return;
  int j=i&7, lane=(i>>3)&63, frag=i>>9;
  int nt = frag%3, kt = frag/3;
  int oc = nt*16 + (lane&15);
  int k  = kt*32 + ((lane>>4)<<3) + j;
  float v = (k < cin) ? W[srcoff + oc*cin + k] : 0.f;
  ((bf16*)(W + dstoff))[i] = __float2bfloat16(v);
}
// pack W1P [8 par][48 oc][64 c] -> frags [par][kt][nt][lane][8]
__global__ __launch_bounds__(256) void k_packi1(float* __restrict__ W){
  int i = blockIdx.x*256 + threadIdx.x;
  if(i >= 24576) return;
  int j=i&7, lane=(i>>3)&63, frag=i>>9;   // frag 0..47
  int par = frag/6, rem = frag%6;
  int kt = rem/3, nt = rem%3;
  int oc = nt*16 + (lane&15);
  int k  = kt*32 + ((lane>>4)<<3) + j;
  ((bf16*)(W + W_WBI))[i] = __float2bfloat16(W[W_W1P + par*3072 + oc*64 + k]);
}

// ---------------- i1 MFMA: folded deconv+w1, x (NCDHW mix) -> O1 NHWC 48ch + stats set0
__global__ __launch_bounds__(256) void k_i1mm(const void* __restrict__ x, const float* __restrict__ W,
    bf16* __restrict__ out, float* __restrict__ stato, const float* __restrict__ flag)
{
  const int f = (int)flag[0];
  const int tid = threadIdx.x, wid = tid>>6, lane = tid&63;
  const int w = blockIdx.x*4 + wid;            // < 3456
  const int b = w/864, t = w%864;
  const int vc0 = t*16;                        // coarse voxel base (13824 per batch)
  const int m = lane&15, quad = lane>>4;
  const short8x* wbI = (const short8x*)(W + W_WBI);

  short8x ah[2], al[2];
  #pragma unroll
  for(int kt=0;kt<2;kt++){
    short hh[8], ll[8];
    #pragma unroll
    for(int j=0;j<8;j++){
      int k = kt*32 + quad*8 + j;
      float v = ldmix(x, ((size_t)(b*64 + k))*13824 + vc0 + m, f);
      bf16 h = __float2bfloat16(v);
      float hf = __bfloat162float(h);
      bf16 l = __float2bfloat16(v - hf);
      __builtin_memcpy(&hh[j], &h, 2); __builtin_memcpy(&ll[j], &l, 2);
    }
    __builtin_memcpy(&ah[kt], hh, 16); __builtin_memcpy(&al[kt], ll, 16);
  }

  f32x4 acc[8][3];
  #pragma unroll
  for(int p=0;p<8;p++)
    #pragma unroll
    for(int nt=0;nt<3;nt++) acc[p][nt] = (f32x4){0.f,0.f,0.f,0.f};

  #pragma unroll
  for(int par=0;par<8;par++){
    #pragma unroll
    for(int kt=0;kt<2;kt++){
      #pragma unroll
      for(int nt=0;nt<3;nt++){
        short8x bfr = wbI[(size_t)((par*2+kt)*3+nt)*64 + lane];
        acc[par][nt] = __builtin_amdgcn_mfma_f32_16x16x32_bf16(ah[kt], bfr, acc[par][nt], 0,0,0);
        acc[par][nt] = __builtin_amdgcn_mfma_f32_16x16x32_bf16(al[kt], bfr, acc[par][nt], 0,0,0);
      }
    }
  }

  // epilogue: bias + stats + LDS repack -> vector global stores
  __shared__ bf16 lds[4][128][48];
  __shared__ float sred[4][12];
  const float* bp = W + W_B1F;
  float sl[3] = {0,0,0}, ssl[3] = {0,0,0};
  #pragma unroll
  for(int nt=0;nt<3;nt++){
    int oc = nt*16 + m;
    float bias = bp[oc];
    #pragma unroll
    for(int par=0;par<8;par++){
      #pragma unroll
      for(int r=0;r<4;r++){
        float v = acc[par][nt][r] + bias;
        int vid = (quad*4+r)*8 + par;
        lds[wid][vid][oc] = __float2bfloat16(v);
        sl[nt] += v; ssl[nt] += v*v;
      }
    }
  }
  #pragma unroll
  for(int nt=0;nt<3;nt++){
    float a = sl[nt], s2 = ssl[nt];
    a += __shfl_xor(a,16); s2 += __shfl_xor(s2,16);
    a += __shfl_xor(a,32); s2 += __shfl_xor(s2,32);
    a += __shfl_xor(a,1);  s2 += __shfl_xor(s2,1);
    a += __shfl_xor(a,2);  s2 += __shfl_xor(s2,2);
    a += __shfl_xor(a,4);  s2 += __shfl_xor(s2,4);
    if(quad==0 && (m&7)==0){
      int g = nt*2 + (m>>3);
      sred[wid][g] = a; sred[wid][6+g] = s2;
    }
  }
  // wave-internal LDS read (no barrier needed) -> 96B vector stores per voxel
  #pragma unroll
  for(int i=0;i<2;i++){
    int vid = lane*2 + i;
    int mm = vid>>3, par = vid&7;
    int vcm = vc0 + mm;
    int xh = vcm%24, yh = (vcm/24)%24, zh = vcm/576;
    int pz = par>>2, py = (par>>1)&1, px = par&1;
    size_t vout = (size_t)(2*zh+pz)*2304 + (2*yh+py)*48 + (2*xh+px);
    uint4x* dst = (uint4x*)(out + ((size_t)b*NVLL + vout)*48);
    const uint4x* srcl = (const uint4x*)&lds[wid][vid][0];
    #pragma unroll
    for(int q=0;q<6;q++) dst[q] = srcl[q];
  }
  __syncthreads();
  if(tid < 12){
    int bb = (blockIdx.x*4)/864;
    float v = sred[0][tid]+sred[1][tid]+sred[2][tid]+sred[3][tid];
    int g = tid%6, kind = tid/6;
    atomicAdd(&stato[(blockIdx.x&(NSH-1))*STSTRIDE + (kind?24:0) + bb*6+g], v);
  }
}

// ---------------- MFMA 1x1 conv: NHWC(48) or NCDHW-mix(32) in -> NHWC 48 out + GN stats
template<int CIN, bool MIX>
__global__ __launch_bounds__(256) void k_c1mm(const void* in, const bf16* __restrict__ wbf,
    const float* __restrict__ bias, bf16* out, float* __restrict__ stato, int set_out,
    const float* __restrict__ flag)
{
  constexpr int KT = (CIN+31)/32;
  const int f = MIX ? (int)flag[0] : 0;
  const int tid = threadIdx.x, wid = tid>>6, lane = tid&63;
  const int w = blockIdx.x*4 + wid;            // < 27648
  const size_t v0g = (size_t)w*16;
  const int b = (int)(v0g/NVLL);
  const size_t v0l = v0g - (size_t)b*NVLL;
  const int m = lane&15, quad = lane>>4;
  const short8x* wb8 = (const short8x*)wbf;
  const short8x zf = {0,0,0,0,0,0,0,0};

  short8x afh[KT], afl[MIX?KT:1];
  #pragma unroll
  for(int kt=0;kt<KT;kt++){
    if constexpr(MIX){
      short hh[8], ll[8];
      #pragma unroll
      for(int j=0;j<8;j++){
        int ch = kt*32 + quad*8 + j;
        float v = ldmix(in, ((size_t)(b*CIN+ch))*NVLL + v0l + m, f);
        bf16 h = __float2bfloat16(v);
        float hf = __bfloat162float(h);
        bf16 l = __float2bfloat16(v - hf);
        __builtin_memcpy(&hh[j], &h, 2); __builtin_memcpy(&ll[j], &l, 2);
      }
      __builtin_memcpy(&afh[kt], hh, 16); __builtin_memcpy(&afl[kt], ll, 16);
    } else {
      int k0 = kt*32 + quad*8;
      short8x a = (k0 < CIN) ? *(const short8x*)((const bf16*)in + (v0g + m)*48 + k0) : zf;
      afh[kt] = a;
    }
  }

  f32x4 acc[3];
  #pragma unroll
  for(int nt=0;nt<3;nt++) acc[nt] = (f32x4){0.f,0.f,0.f,0.f};
  #pragma unroll
  for(int kt=0;kt<KT;kt++){
    #pragma unroll
    for(int nt=0;nt<3;nt++){
      short8x bfr = wb8[(size_t)(kt*3+nt)*64 + lane];
      acc[nt] = __builtin_amdgcn_mfma_f32_16x16x32_bf16(afh[kt], bfr, acc[nt], 0,0,0);
      if constexpr(MIX)
        acc[nt] = __builtin_amdgcn_mfma_f32_16x16x32_bf16(afl[kt], bfr, acc[nt], 0,0,0);
    }
  }

  __shared__ bf16 lds[4][16][48];
  __shared__ float sred[4][12];
  float sl[3] = {0,0,0}, ssl[3] = {0,0,0};
  #pragma unroll
  for(int nt=0;nt<3;nt++){
    int oc = nt*16 + m;
    float bv = bias[oc];
    #pragma unroll
    for(int r=0;r<4;r++){
      float v = acc[nt][r] + bv;
      lds[wid][quad*4+r][oc] = __float2bfloat16(v);
      sl[nt] += v; ssl[nt] += v*v;
    }
  }
  #pragma unroll
  for(int nt=0;nt<3;nt++){
    float a = sl[nt], s2 = ssl[nt];
    a += __shfl_xor(a,16); s2 += __shfl_xor(s2,16);
    a += __shfl_xor(a,32); s2 += __shfl_xor(s2,32);
    a += __shfl_xor(a,1);  s2 += __shfl_xor(s2,1);
    a += __shfl_xor(a,2);  s2 += __shfl_xor(s2,2);
    a += __shfl_xor(a,4);  s2 += __shfl_xor(s2,4);
    if(quad==0 && (m&7)==0){
      int g = nt*2 + (m>>3);
      sred[wid][g] = a; sred[wid][6+g] = s2;
    }
  }
  if(lane < 16){
    uint4x* dst = (uint4x*)(out + (v0g + lane)*48);
    const uint4x* srcl = (const uint4x*)&lds[wid][lane][0];
    #pragma unroll
    for(int q=0;q<6;q++) dst[q] = srcl[q];
  }
  __syncthreads();
  if(tid < 12){
    int bb = (int)(((size_t)(blockIdx.x*4)*16)/NVLL);
    float v = sred[0][tid]+sred[1][tid]+sred[2][tid]+sred[3][tid];
    int g = tid%6, kind = tid/6;
    atomicAdd(&stato[(blockIdx.x&(NSH-1))*STSTRIDE + set_out*48 + (kind?24:0) + bb*6+g], v);
  }
}

// ---------------- GN apply + leaky(0.1), NHWC vectorized, shard-summed stats -----------
__global__ __launch_bounds__(256) void k_gn_apply(bf16* buf, const float* __restrict__ stats, int set,
    const float* __restrict__ gamma, const float* __restrict__ beta)
{
  const int v = blockIdx.x*256 + threadIdx.x;
  const int b = blockIdx.y;
  __shared__ float sm[12];
  if(threadIdx.x < 12){
    int kind = threadIdx.x/6, g = threadIdx.x%6;
    int off = set*48 + (kind?24:0) + b*6+g;
    float s = 0.f;
    for(int sh=0; sh<NSH; sh++) s += stats[sh*STSTRIDE + off];
    sm[threadIdx.x] = s;
  }
  __syncthreads();
  const float invN = 1.0f/(8.0f*(float)NV);
  float m[6], rs[6];
  #pragma unroll
  for(int g=0;g<6;g++){
    float mm = sm[g]*invN;
    float var = sm[6+g]*invN - mm*mm;
    m[g] = mm; rs[g] = rsqrtf(var + 1e-5f);
  }
  uint4x* p4 = (uint4x*)(buf + ((size_t)b*NVLL + v)*48);
  uint4x w6[6];
  #pragma unroll
  for(int q=0;q<6;q++) w6[q] = p4[q];
  unsigned int* wu = (unsigned int*)w6;
  #pragma unroll
  for(int c2=0;c2<24;c2++){
    int c0 = 2*c2;
    float x0 = lo2f(wu[c2]), x1 = hi2f(wu[c2]);
    int g0 = c0>>3, g1 = (c0+1)>>3;
    x0 = (x0 - m[g0])*rs[g0]*gamma[c0] + beta[c0];
    x1 = (x1 - m[g1])*rs[g1]*gamma[c0+1] + beta[c0+1];
    x0 = x0 < 0.f ? 0.1f*x0 : x0;
    x1 = x1 < 0.f ? 0.1f*x1 : x1;
    wu[c2] = pk2(x0, x1);
  }
  #pragma unroll
  for(int q=0;q<6;q++) p4[q] = w6[q];
}

// ---------------- pool 48^3 -> 6^3 (vectorized NHWC loads) ----------------
__global__ __launch_bounds__(512) void k_pool2(const bf16* __restrict__ s0, const bf16* __restrict__ s1,
    float* __restrict__ d0, float* __restrict__ d1)
{
  const int which = blockIdx.y;
  const bf16* src = which ? s1 : s0;
  float*      dst = which ? d1 : d0;
  const int cell = blockIdx.x % 216, b = blockIdx.x/216;
  const int tid = threadIdx.x;
  const int cz=cell/36, cy=(cell/6)%6, cx=cell%6;
  const int dz=tid>>6, dy=(tid>>3)&7, dx=tid&7;
  const size_t vox = (size_t)(cz*8+dz)*2304 + (cy*8+dy)*48 + (cx*8+dx);
  const uint4x* p4 = (const uint4x*)(src + ((size_t)b*NVLL + vox)*48);
  uint4x w6[6];
  #pragma unroll
  for(int q=0;q<6;q++) w6[q] = p4[q];
  const unsigned int* wu = (const unsigned int*)w6;
  float val[48];
  #pragma unroll
  for(int c2=0;c2<24;c2++){ val[2*c2] = lo2f(wu[c2]); val[2*c2+1] = hi2f(wu[c2]); }
  __shared__ float rmax[8][48], rsum[8][48];
  const int wid=tid>>6, lane=tid&63;
  #pragma unroll
  for(int o=0;o<48;o++){
    float mx=val[o], sm=val[o];
    #pragma unroll
    for(int s=32;s>=1;s>>=1){ mx=fmaxf(mx,__shfl_xor(mx,s)); sm+=__shfl_xor(sm,s); }
    if(lane==0){ rmax[wid][o]=mx; rsum[wid][o]=sm; }
  }
  __syncthreads();
  if(tid<48){
    float mx=rmax[0][tid], sm=rsum[0][tid];
    #pragma unroll
    for(int w2=1;w2<8;w2++){ mx=fmaxf(mx,rmax[w2][tid]); sm+=rsum[w2][tid]; }
    dst[(size_t)(b*48+tid)*216 + cell] = mx + sm*(1.f/512.f);
  }
}

// ---------------- fused conv1x1(concat(xe, folded-x0)) + pool -> pkv -------------------
__global__ __launch_bounds__(512) void k_poolfuse(const void* __restrict__ xe, const void* __restrict__ x,
    const float* __restrict__ W, float* __restrict__ pkv, const float* __restrict__ flag)
{
  const int f = (int)flag[0];
  const int cell = blockIdx.x % 216;
  const int b = blockIdx.x / 216;
  const int tid = threadIdx.x;
  const int cz = cell/36, cy = (cell/6)%6, cx = cell%6;
  const int dz = tid>>6, dy = (tid>>3)&7, dx = tid&7;
  const int gz = cz*8+dz, gy = cy*8+dy, gx = cx*8+dx;
  const size_t voff = (size_t)gz*2304 + gy*48 + gx;
  const int par = ((gz&1)<<2) | ((gy&1)<<1) | (gx&1);
  const int vh = (gz>>1)*576 + (gy>>1)*24 + (gx>>1);
  float xev[32], xrv[64];
  #pragma unroll
  for(int c=0;c<32;c++) xev[c] = ldmix(xe, ((size_t)(b*32+c))*NVLL + voff, f);
  #pragma unroll
  for(int c=0;c<64;c++) xrv[c] = ldmix(x, (size_t)(b*64+c)*13824 + vh, f);
  const float* wf  = W + W_WF;
  const float* wfp = W + W_WFP + par*3072;
  const float* bff = W + W_BFF;
  __shared__ float rmax[8][48];
  __shared__ float rsum[8][48];
  const int wid = tid>>6, lane = tid&63;
  #pragma unroll
  for(int o=0;o<48;o++){
    float acc = bff[o];
    #pragma unroll
    for(int c=0;c<32;c++) acc += wf[o*64+c]*xev[c];
    #pragma unroll
    for(int c=0;c<64;c++) acc += wfp[o*64+c]*xrv[c];
    float mx = acc, sm = acc;
    #pragma unroll
    for(int s=32;s>=1;s>>=1){ mx = fmaxf(mx, __shfl_xor(mx,s)); sm += __shfl_xor(sm,s); }
    if(lane==0){ rmax[wid][o] = mx; rsum[wid][o] = sm; }
  }
  __syncthreads();
  if(tid < 48){
    float mx = rmax[0][tid], sm = rsum[0][tid];
    #pragma unroll
    for(int w2=1;w2<8;w2++){ mx = fmaxf(mx, rmax[w2][tid]); sm += rsum[w2][tid]; }
    pkv[((size_t)(b*48+tid))*216 + cell] = mx + sm*(1.f/512.f);
  }
}

// ---------------- linear cross-attention ----------------
__global__ __launch_bounds__(256) void k_attn(const float* __restrict__ p1, const float* __restrict__ p2,
    const float* __restrict__ pkv, const float* __restrict__ W, float* __restrict__ a1, float* __restrict__ a2)
{
  const int which = blockIdx.x, b = blockIdx.y;
  const float* wb = W + W_ATT + which*9408;
  const float* wq = wb;        const float* bq = wb+2304;
  const float* wk = wb+2352;   const float* bk = wb+4656;
  const float* wv = wb+4704;   const float* bv = wb+7008;
  const float* wo = wb+7056;   const float* bo = wb+9360;
  const float* q   = which ? p2 : p1;
  float*       aout= which ? a2 : a1;
  const float* kvb = pkv + (size_t)b*48*216;
  const float* qb  = q   + (size_t)b*48*216;
  __shared__ float kh[216*48];
  __shared__ float ctx[288];
  const int tid = threadIdx.x;

  if(tid < 216){
    float kvr[48];
    #pragma unroll
    for(int c=0;c<48;c++) kvr[c] = kvb[c*216 + tid];
    #pragma unroll
    for(int o=0;o<48;o++){
      float acc = bk[o];
      #pragma unroll
      for(int c=0;c<48;c++) acc += kvr[c]*wk[o*48+c];
      kh[tid*48+o] = acc;
    }
  }
  __syncthreads();
  if(tid < 48){
    float mx = -1e30f;
    for(int n=0;n<216;n++) mx = fmaxf(mx, kh[n*48+tid]);
    float s = 0.f;
    for(int n=0;n<216;n++){ float e = __expf(kh[n*48+tid]-mx); kh[n*48+tid] = e; s += e; }
    float inv = 1.f/s;
    for(int n=0;n<216;n++) kh[n*48+tid] *= inv;
  }
  __syncthreads();
  if(tid < 48){
    int h = tid/6, e = tid%6;
    float cacc[6] = {0,0,0,0,0,0};
    for(int n=0;n<216;n++){
      float vh = bv[h*6+e];
      #pragma unroll
      for(int c=0;c<48;c++) vh += kvb[c*216+n]*wv[(h*6+e)*48+c];
      #pragma unroll
      for(int d=0;d<6;d++) cacc[d] += kh[n*48 + h*6+d]*vh;
    }
    #pragma unroll
    for(int d=0;d<6;d++) ctx[(h*6+d)*6+e] = cacc[d];
  }
  __syncthreads();
  if(tid < 216){
    int n = tid;
    float qr[48];
    #pragma unroll
    for(int c=0;c<48;c++) qr[c] = qb[c*216 + n];
    float qh[48];
    #pragma unroll
    for(int o=0;o<48;o++){
      float acc = bq[o];
      #pragma unroll
      for(int c=0;c<48;c++) acc += qr[c]*wq[o*48+c];
      qh[o] = acc;
    }
    #pragma unroll
    for(int h=0;h<8;h++){
      float mx = qh[h*6];
      #pragma unroll
      for(int d=1;d<6;d++) mx = fmaxf(mx, qh[h*6+d]);
      float s = 0.f;
      #pragma unroll
      for(int d=0;d<6;d++){ float e = __expf(qh[h*6+d]-mx); qh[h*6+d] = e; s += e; }
      float inv = 1.f/s;
      #pragma unroll
      for(int d=0;d<6;d++) qh[h*6+d] *= inv;
    }
    float ov[48];
    #pragma unroll
    for(int h=0;h<8;h++){
      #pragma unroll
      for(int e=0;e<6;e++){
        float acc = 0.f;
        #pragma unroll
        for(int d=0;d<6;d++) acc += qh[h*6+d]*ctx[(h*6+d)*6+e];
        ov[h*6+e] = acc;
      }
    }
    #pragma unroll
    for(int o=0;o<48;o++){
      float acc = bo[o];
      #pragma unroll
      for(int c=0;c<48;c++) acc += ov[c]*wo[o*48+c];
      aout[((size_t)(b*48+o))*216 + n] = acc;
    }
  }
}

// ---------------- gate: i1 *= sig(up(a1)), i2 *= sig(up(a2)), vectorized ----------------
__device__ inline void interp1(int u, int& i0, int& i1, float& t){
  float pos = u * (5.0f/47.0f);
  float f = floorf(pos);
  i0 = (int)f; if(i0 > 5) i0 = 5;
  i1 = i0+1 > 5 ? 5 : i0+1;
  t = pos - f; if(t < 0.f) t = 0.f; if(t > 1.f) t = 1.f;
}

__global__ __launch_bounds__(256) void k_gate(bf16* i1b, bf16* i2b,
    const float* __restrict__ a1, const float* __restrict__ a2)
{
  const int v = blockIdx.x*256 + threadIdx.x;
  const int b = blockIdx.y;
  const int x = v % 48, y = (v/48) % 48, z = v/2304;
  int xi0,xi1,yi0,yi1,zi0,zi1; float xt,yt,zt;
  interp1(x,xi0,xi1,xt); interp1(y,yi0,yi1,yt); interp1(z,zi0,zi1,zt);
  int off[8]; float cw[8];
  off[0]=zi0*36+yi0*6+xi0; cw[0]=(1-zt)*(1-yt)*(1-xt);
  off[1]=zi0*36+yi0*6+xi1; cw[1]=(1-zt)*(1-yt)*xt;
  off[2]=zi0*36+yi1*6+xi0; cw[2]=(1-zt)*yt*(1-xt);
  off[3]=zi0*36+yi1*6+xi1; cw[3]=(1-zt)*yt*xt;
  off[4]=zi1*36+yi0*6+xi0; cw[4]=zt*(1-yt)*(1-xt);
  off[5]=zi1*36+yi0*6+xi1; cw[5]=zt*(1-yt)*xt;
  off[6]=zi1*36+yi1*6+xi0; cw[6]=zt*yt*(1-xt);
  off[7]=zi1*36+yi1*6+xi1; cw[7]=zt*yt*xt;
  const float* A1b = a1 + (size_t)b*48*216;
  const float* A2b = a2 + (size_t)b*48*216;

  uint4x* p14 = (uint4x*)(i1b + ((size_t)b*NVLL + v)*48);
  uint4x* p24 = (uint4x*)(i2b + ((size_t)b*NVLL + v)*48);
  uint4x w6[6];
  #pragma unroll
  for(int q=0;q<6;q++) w6[q] = p14[q];
  unsigned int* wu = (unsigned int*)w6;
  #pragma unroll
  for(int c2=0;c2<24;c2++){
    int c0 = 2*c2;
    float s0 = 0.f, s1 = 0.f;
    #pragma unroll
    for(int k=0;k<8;k++){ s0 += cw[k]*A1b[c0*216+off[k]]; s1 += cw[k]*A1b[(c0+1)*216+off[k]]; }
    s0 = 1.f/(1.f + __expf(-s0));
    s1 = 1.f/(1.f + __expf(-s1));
    wu[c2] = pk2(s0*lo2f(wu[c2]), s1*hi2f(wu[c2]));
  }
  #pragma unroll
  for(int q=0;q<6;q++) p14[q] = w6[q];

  #pragma unroll
  for(int q=0;q<6;q++) w6[q] = p24[q];
  #pragma unroll
  for(int c2=0;c2<24;c2++){
    int c0 = 2*c2;
    float s0 = 0.f, s1 = 0.f;
    #pragma unroll
    for(int k=0;k<8;k++){ s0 += cw[k]*A2b[c0*216+off[k]]; s1 += cw[k]*A2b[(c0+1)*216+off[k]]; }
    s0 = 1.f/(1.f + __expf(-s0));
    s1 = 1.f/(1.f + __expf(-s1));
    wu[c2] = pk2(s0*lo2f(wu[c2]), s1*hi2f(wu[c2]));
  }
  #pragma unroll
  for(int q=0;q<6;q++) p24[q] = w6[q];
}

// ---------------- MFMA implicit-GEMM 3x3x3 conv, block-reduced sharded stats -----------
template<int KT, bool TWO, bool USETB>
__global__ __launch_bounds__(256) void k_conv3m(
    const bf16* __restrict__ in0, const bf16* __restrict__ in1,
    const bf16* __restrict__ wb, const float* __restrict__ tb, const float* __restrict__ cb,
    bf16* __restrict__ outp, float* __restrict__ stato, int sOut, int bidx, int onhwc)
{
  const int tid = threadIdx.x;
  const int wid = tid>>6, lane = tid&63;
  const int run = blockIdx.x*4 + wid;          // 6912 runs
  const int x0 = (run%3)*16, y = (run/3)%48, z = run/144;
  const int m = lane&15, quad = lane>>4;
  const int CB = TWO ? 48 : 32;
  const int k0 = quad*8;
  const short8x* wb8 = (const short8x*)wb;
  const short8x zf = {0,0,0,0,0,0,0,0};

  f32x4 acc0 = {0.f,0.f,0.f,0.f};
  f32x4 acc1 = {0.f,0.f,0.f,0.f};

  for(int dz=0; dz<3; dz++){
    int zz = z + dz - 1;
    if(zz < 0 || zz >= 48) continue;
    for(int dy=0; dy<3; dy++){
      int yy = y + dy - 1;
      if(yy < 0 || yy >= 48) continue;
      #pragma unroll
      for(int dx=0; dx<3; dx++){
        int xx = x0 + m + dx - 1;
        bool ok = (xx >= 0 && xx < 48);
        int xc = xx < 0 ? 0 : (xx > 47 ? 47 : xx);
        int vox = zz*2304 + yy*48 + xc;
        int tap = dz*9 + dy*3 + dx;
        #pragma unroll
        for(int kt=0; kt<KT; kt++){
          int kk = kt*32 + k0;
          const bf16* src; int ch;
          if(TWO){ if(kk < 48){ src = in0; ch = kk; } else { src = in1; ch = kk-48; } }
          else    { src = in0; ch = kk; }
          short8x af = *(const short8x*)(src + (size_t)vox*CB + ch);
          if(!ok) af = zf;
          short8x b0 = wb8[ (size_t)((tap*KT + kt)*2 + 0)*64 + lane ];
          short8x b1 = wb8[ (size_t)((tap*KT + kt)*2 + 1)*64 + lane ];
          acc0 = __builtin_amdgcn_mfma_f32_16x16x32_bf16(af, b0, acc0, 0,0,0);
          acc1 = __builtin_amdgcn_mfma_f32_16x16x32_bf16(af, b1, acc1, 0,0,0);
        }
      }
    }
  }

  const int oc0 = m, oc1 = 16 + m;
  float s0=0.f, ss0=0.f, s1=0.f, ss1=0.f;
  #pragma unroll
  for(int r=0;r<4;r++){
    int mv = quad*4 + r;
    int xr = x0 + mv;
    float b0v = cb[oc0], b1v = cb[oc1];
    if constexpr(USETB){
      #pragma unroll
      for(int t=0;t<27;t++){
        int tdz = t/9, tdy = (t/3)%3, tdx = t%3;
        int zz = z+tdz-1, yy = y+tdy-1, xx = xr+tdx-1;
        if(zz>=0 && zz<48 && yy>=0 && yy<48 && xx>=0 && xx<48){
          b0v += tb[t*32+oc0]; b1v += tb[t*32+oc1];
        }
      }
    }
    float v0 = acc0[r] + b0v;
    float v1 = acc1[r] + b1v;
    size_t vox = (size_t)z*2304 + y*48 + xr;
    if(onhwc){
      outp[vox*32 + oc0] = __float2bfloat16(v0);
      outp[vox*32 + oc1] = __float2bfloat16(v1);
    } else {
      outp[(size_t)oc0*NVLL + vox] = __float2bfloat16(v0);
      outp[(size_t)oc1*NVLL + vox] = __float2bfloat16(v1);
    }
    s0 += v0; ss0 += v0*v0; s1 += v1; ss1 += v1*v1;
  }
  s0 += __shfl_xor(s0,16); ss0 += __shfl_xor(ss0,16); s1 += __shfl_xor(s1,16); ss1 += __shfl_xor(ss1,16);
  s0 += __shfl_xor(s0,32); ss0 += __shfl_xor(ss0,32); s1 += __shfl_xor(s1,32); ss1 += __shfl_xor(ss1,32);
  __shared__ float csum[4][32], css[4][32];
  if(quad==0){
    csum[wid][oc0]=s0; css[wid][oc0]=ss0;
    csum[wid][oc1]=s1; css[wid][oc1]=ss1;
  }
  __syncthreads();
  if(tid < 64){
    int oc = tid&31, kind = tid>>5;
    float v = kind ? (css[0][oc]+css[1][oc]+css[2][oc]+css[3][oc])
                   : (csum[0][oc]+csum[1][oc]+csum[2][oc]+csum[3][oc]);
    atomicAdd(&stato[(blockIdx.x&(NSH-1))*STSTRIDE + sOut + (kind?128:0) + bidx*32 + oc], v);
  }
}

// ---------------- IN + leaky(0.01) on h1 (NHWC), shard-summed stats --------------------
struct P4 { bf16* p[4]; };
__global__ __launch_bounds__(256) void k_inleak(P4 h1, const float* __restrict__ stats){
  int gid = blockIdx.x*256 + threadIdx.x;      // grid 1728: thread per voxel
  int b = gid/NV; int v = gid - b*NV;
  __shared__ float sm2[64];
  if(threadIdx.x < 64){
    int oc = threadIdx.x&31, kind = threadIdx.x>>5;
    int off = 192 + (kind?128:0) + b*32 + oc;
    float s = 0.f;
    for(int sh=0; sh<NSH; sh++) s += stats[sh*STSTRIDE + off];
    sm2[threadIdx.x] = s;
  }
  __syncthreads();
  const float invN = 1.f/(float)NV;
  uint4x* p4 = (uint4x*)(h1.p[b] + (size_t)v*32);
  uint4x w4[4];
  #pragma unroll
  for(int q=0;q<4;q++) w4[q] = p4[q];
  unsigned int* wu = (unsigned int*)w4;
  #pragma unroll
  for(int c2=0;c2<16;c2++){
    int c0 = 2*c2;
    float m0 = sm2[c0]*invN,   m1 = sm2[c0+1]*invN;
    float r0 = rsqrtf(sm2[32+c0]*invN - m0*m0 + 1e-5f);
    float r1 = rsqrtf(sm2[32+c0+1]*invN - m1*m1 + 1e-5f);
    float x0 = (lo2f(wu[c2]) - m0)*r0;
    float x1 = (hi2f(wu[c2]) - m1)*r1;
    x0 = x0 < 0.f ? 0.01f*x0 : x0;
    x1 = x1 < 0.f ? 0.01f*x1 : x1;
    wu[c2] = pk2(x0, x1);
  }
  #pragma unroll
  for(int q=0;q<4;q++) p4[q] = w4[q];
}

// ---------------- final IN + leaky(0.01): h2 slabs (NCHW) -> d_out, shard-summed -------
__global__ __launch_bounds__(256) void k_in_final(P4 h2, const float* __restrict__ stats,
    void* out, const float* __restrict__ flag)
{
  const int f = (int)flag[0];
  int gid = blockIdx.x*256 + threadIdx.x;      // grid 6912 blocks, 8 elem/thread
  size_t i8 = (size_t)gid*8;
  int b = (int)(i8/(NV*32)); int j = (int)(i8 - (size_t)b*(NV*32));
  int c = j/NV;
  // block covers 2048 consecutive elements: at most 2 channels, single batch
  size_t i80 = (size_t)(blockIdx.x*256)*8;
  int b0 = (int)(i80/(NV*32)); int j0 = (int)(i80 - (size_t)b0*(NV*32));
  int c0 = j0/NV;
  __shared__ float sm2[4];
  if(threadIdx.x < 4){
    int dc = threadIdx.x>>1, kind = threadIdx.x&1;
    int cc = c0+dc > 31 ? 31 : c0+dc;
    int off = 448 + (kind?128:0) + b0*32 + cc;
    float s = 0.f;
    for(int sh=0; sh<NSH; sh++) s += stats[sh*STSTRIDE + off];
    sm2[threadIdx.x] = s;
  }
  __syncthreads();
  const float invN = 1.f/(float)NV;
  int dc = c - c0;
  float m = sm2[dc*2]*invN;
  float var = sm2[dc*2+1]*invN - m*m;
  float rs = rsqrtf(var + 1e-5f);
  uint4x w = *(uint4x*)(h2.p[b] + j);
  const unsigned int* wu = (const unsigned int*)&w;
  float vv[8];
  #pragma unroll
  for(int k2=0;k2<4;k2++){ vv[2*k2] = lo2f(wu[k2]); vv[2*k2+1] = hi2f(wu[k2]); }
  #pragma unroll
  for(int k=0;k<8;k++){
    float xv = (vv[k]-m)*rs;
    vv[k] = xv < 0.f ? 0.01f*xv : xv;
  }
  if(f){
    float* op = (float*)out + i8;
    uint4x o0, o1;
    __builtin_memcpy(&o0, &vv[0], 16);
    __builtin_memcpy(&o1, &vv[4], 16);
    ((uint4x*)op)[0] = o0; ((uint4x*)op)[1] = o1;
  } else {
    unsigned int pk[4];
    #pragma unroll
    for(int k2=0;k2<4;k2++) pk[k2] = pk2(vv[2*k2], vv[2*k2+1]);
    *(uint4x*)((bf16*)out + i8) = *(uint4x*)pk;
  }
}

// ==========================================================================
extern "C" void kernel_launch(void* const* d_in, const int* in_sizes, int n_in,
                              void* d_out, int out_size, void* d_ws, size_t ws_size,
                              hipStream_t stream)
{
  (void)in_sizes; (void)n_in; (void)out_size; (void)ws_size;
  char* base = (char*)d_ws;
  const void* x  = d_in[0];
  const void* xe = d_in[1];

  float* SM  = (float*)base;
  float* P1  = SM + SM_P1;
  float* P2  = SM + SM_P2;
  float* PKV = SM + SM_PKV;
  float* A1  = SM + SM_A1;
  float* A2  = SM + SM_A2;
  float* ST  = SM + SM_ST;
  float* W   = SM + SM_W;
  float* FL  = SM + SM_FL;
  bf16*  O1  = (bf16*)(base + BOFF_O1);
  bf16*  O2  = (bf16*)(base + BOFF_O2);

  P4 H1, H2;
  H1.p[0] = (bf16*)(base + BOFF_SP);
  H1.p[1] = (bf16*)(base + BOFF_O1);
  H1.p[2] = (bf16*)(base + BOFF_O1 + SLOT48);
  H1.p[3] = (bf16*)(base + BOFF_O1 + 2*SLOT48);
  for(int b=0;b<4;b++) H2.p[b] = (bf16*)(base + BOFF_O2 + (size_t)b*SLOT48);

  k_detect<<<1, 256, 0, stream>>>(xe, FL);
  k_zero<<<(NSH*STSTRIDE+255)/256, 256, 0, stream>>>(ST);

  PtrTab pt;
  for(int i=0;i<36;i++) pt.p[i] = d_in[i+2];
  k_prep<<<(W_TOTAL+255)/256, 256, 0, stream>>>(pt, W, FL);
  k_fold <<<193, 256, 0, stream>>>(W);
  k_fold2<<<328, 256, 0, stream>>>(W);
  k_packb1<<<324, 256, 0, stream>>>(W);
  k_packb2<<<108, 256, 0, stream>>>(W);
  k_packc<<<6,  256, 0, stream>>>(W, W_W2, 32, 1, W_WB3);
  k_packc<<<12, 256, 0, stream>>>(W, W_W3, 48, 2, W_WB4);
  k_packc<<<12, 256, 0, stream>>>(W, W_W4, 48, 2, W_WB5);
  k_packi1<<<96, 256, 0, stream>>>(W);

  const float* gam = W + W_GNG;
  const float* bet = W + W_GNB;

  // i1 branch -> O1 (NHWC): MFMA deconv+w1, GN(0), MFMA w3, GN(1)
  k_i1mm<<<864, 256, 0, stream>>>(x, W, O1, ST, FL);
  k_gn_apply<<<dim3(432,4), 256, 0, stream>>>(O1, ST, 0, gam, bet);
  k_c1mm<48,false><<<6912, 256, 0, stream>>>(O1, (const bf16*)(W+W_WB4), W+W_B3, O1, ST, 1, FL);
  k_gn_apply<<<dim3(432,4), 256, 0, stream>>>(O1, ST, 1, gam, bet);

  // i2 branch -> O2 (NHWC): MFMA w2 (mix), GN(2), MFMA w4, GN(3)
  k_c1mm<32,true ><<<6912, 256, 0, stream>>>(xe, (const bf16*)(W+W_WB3), W+W_B2, O2, ST, 2, FL);
  k_gn_apply<<<dim3(432,4), 256, 0, stream>>>(O2, ST, 2, gam, bet);
  k_c1mm<48,false><<<6912, 256, 0, stream>>>(O2, (const bf16*)(W+W_WB5), W+W_B4, O2, ST, 3, FL);
  k_gn_apply<<<dim3(432,4), 256, 0, stream>>>(O2, ST, 3, gam, bet);

  // pools + attention
  k_pool2<<<dim3(864,2), 512, 0, stream>>>(O1, O2, P1, P2);
  k_poolfuse<<<864, 512, 0, stream>>>(xe, x, W, PKV, FL);
  k_attn<<<dim3(2,4), 256, 0, stream>>>(P1, P2, PKV, W, A1, A2);

  // gate i1,i2 in place -> o1,o2
  k_gate<<<dim3(432,4), 256, 0, stream>>>(O1, O2, A1, A2);

  // conv#1 (folded with Wfin): 96ch NHWC -> h1 (NHWC 32ch), IN stats @192
  for(int b=0;b<4;b++){
    const bf16* o1b = O1 + (size_t)b*48*NVLL;
    const bf16* o2b = O2 + (size_t)b*48*NVLL;
    k_conv3m<3,true,true><<<1728, 256, 0, stream>>>(o1b, o2b, (const bf16*)(W+W_WB1), W+W_TB, W+W_C0B,
                                                    H1.p[b], ST, 192, b, 1);
  }
  k_inleak<<<1728, 256, 0, stream>>>(H1, ST);

  // conv#2: 32ch NHWC -> h2 (NCHW slab), IN stats @448
  for(int b=0;b<4;b++){
    k_conv3m<1,false,false><<<1728, 256, 0, stream>>>(H1.p[b], nullptr, (const bf16*)(W+W_WB2), nullptr, W+W_C1B,
                                                      H2.p[b], ST, 448, b, 0);
  }
  k_in_final<<<6912, 256, 0, stream>>>(H2, ST, d_out, FL);
}

// Round 9
// 1691.887 us; speedup vs baseline: 3.1521x; 1.0739x over previous
//
#include <hip/hip_runtime.h>
#include <hip/hip_bf16.h>

typedef __hip_bfloat16 bf16;
typedef __attribute__((ext_vector_type(8))) short short8x;
typedef __attribute__((ext_vector_type(4))) float f32x4;
typedef __attribute__((ext_vector_type(4))) unsigned int uint4x;

#define NV 110592           // 48^3
#define NVLL 110592ull
#define NSH 64              // stats shards
#define STSTRIDE 704

__device__ inline float ldmix(const void* p, size_t i, int f){
  return f ? ((const float*)p)[i] : __bfloat162float(((const bf16*)p)[i]);
}
__device__ inline float lo2f(unsigned int u){ union{unsigned int i; float f;} t; t.i = u<<16; return t.f; }
__device__ inline float hi2f(unsigned int u){ union{unsigned int i; float f;} t; t.i = u & 0xffff0000u; return t.f; }
__device__ inline unsigned short bfb(float f){ bf16 h=__float2bfloat16(f); unsigned short u; __builtin_memcpy(&u,&h,2); return u; }
__device__ inline unsigned int pk2(float a, float b){ return (unsigned int)bfb(a) | ((unsigned int)bfb(b)<<16); }

// ---------------- workspace layout (BYTES), total <= 96 MiB ----------------
static const size_t BOFF_O1 = 2621440;
static const size_t BOFF_O2 = 45088768;
static const size_t BOFF_SP = 87556096;
static const size_t SLOT48  = 10616832;
// small-region float offsets
#define SM_P1   0
#define SM_P2   41472
#define SM_PKV  82944
#define SM_A1   124416
#define SM_A2   165888
#define SM_ST   207360   // 64 shards x 704 floats = 45056
#define SM_W    252416

// fp32 weight region offsets (floats, relative to W)
#define W_UPW   0
#define W_UPB   16384
#define W_WF    16416
#define W_BF    19488
#define W_W1    19536
#define W_B1    21072
#define W_W2    21120
#define W_B2    22656
#define W_W3    22704
#define W_B3    25008
#define W_W4    25056
#define W_B4    27360
#define W_GNG   27408
#define W_GNB   27456
#define W_ATT   27504
#define W_WFIN  46320
#define W_BFIN  52464
#define W_C0W   52528
#define W_C0B   107824
#define W_C1W   107856
#define W_C1B   135504
#define W_TOTAL 135536
#define W_W1P   135536   // [8][48][64]
#define W_B1F   160112
#define W_WFP   160160   // [8][48][64]
#define W_BFF   184736
#define W_WP    184784   // fp32 [32 oc][96 k][27 tap]
#define W_TB    267728   // fp32 [27 tap][32 oc]
#define W_WB1   268592   // bf16[82944]  conv3 #1 frags
#define W_WB2   310064   // bf16[27648]  conv3 #2 frags
#define W_WB3   323888   // bf16[1536]   W2 frags (K=32)
#define W_WB4   324656   // bf16[3072]   W3 frags (K=48 padded)
#define W_WB5   326192   // bf16[3072]   W4 frags (K=48 padded)
#define W_WBI   327728   // bf16[24576]  W1P frags [8 par][2 kt][3 nt]
#define SM_FL   604720

// ---------------- dtype detect ----------------
__global__ __launch_bounds__(256) void k_detect(const void* xe, float* __restrict__ flag){
  const bf16* p = (const bf16*)xe;
  int tid = threadIdx.x;
  float mx = 0.f;
  for(int i=tid;i<8192;i+=256){
    float v = fabsf(__bfloat162float(p[i]));
    if(!(v==v)) v = 1e30f;
    mx = fmaxf(mx, v);
  }
  #pragma unroll
  for(int s=32;s>=1;s>>=1) mx = fmaxf(mx, __shfl_xor(mx,s));
  __shared__ float red[4];
  if((tid&63)==0) red[tid>>6] = mx;
  __syncthreads();
  if(tid==0){
    float m = fmaxf(fmaxf(red[0],red[1]), fmaxf(red[2],red[3]));
    flag[0] = (m > 1e3f) ? 1.f : 0.f;
  }
}

__global__ __launch_bounds__(256) void k_zero(float* __restrict__ st){
  int i = blockIdx.x*256 + threadIdx.x;
  if(i < NSH*STSTRIDE) st[i] = 0.f;
}

// ---------------- weight prep ----------------
struct PtrTab { const void* p[36]; };
__device__ const int g_seg[36] = {16384,32,3072,48,1536,48,1536,48,2304,48,2304,48,48,48,
  2304,48,2304,48,2304,48,2304,48,2304,48,2304,48,2304,48,2304,48,6144,64,55296,32,27648,32};

__global__ __launch_bounds__(256) void k_prep(PtrTab t, float* __restrict__ W, const float* __restrict__ flag){
  const int f = (int)flag[0];
  int i = blockIdx.x*256 + threadIdx.x;
  if(i >= W_TOTAL) return;
  int rem = i;
  for(int s=0;s<36;s++){
    int sz = g_seg[s];
    if(rem < sz){ W[i] = ldmix(t.p[s], rem, f); return; }
    rem -= sz;
  }
}

__global__ __launch_bounds__(256) void k_fold(float* __restrict__ W){
  int i = blockIdx.x*256 + threadIdx.x;
  const float* upw = W + W_UPW;
  const float* upb = W + W_UPB;
  if(i < 49152){
    int which = i / 24576;
    int r = i % 24576;
    int par = r / 3072; int o = (r/64)%48; int c = r%64;
    float acc = 0.f;
    for(int m=0;m<32;m++){
      float wm = which ? W[W_WF + o*64 + 32 + m] : W[W_W1 + o*32 + m];
      acc += wm * upw[c*256 + m*8 + par];
    }
    W[(which ? W_WFP : W_W1P) + par*3072 + o*64 + c] = acc;
  } else if(i < 49248){
    int j = i - 49152;
    int which = j / 48; int o = j % 48;
    float acc = which ? W[W_BF + o] : W[W_B1 + o];
    for(int m=0;m<32;m++){
      float wm = which ? W[W_WF + o*64 + 32 + m] : W[W_W1 + o*32 + m];
      acc += wm * upb[m];
    }
    W[(which ? W_BFF : W_B1F) + o] = acc;
  }
}

__global__ __launch_bounds__(256) void k_fold2(float* __restrict__ W){
  int i = blockIdx.x*256 + threadIdx.x;
  if(i < 82944){
    int tap = i%27; int k = (i/27)%96; int oc = i/(27*96);
    float acc = 0.f;
    for(int m=0;m<64;m++) acc += W[W_C0W + oc*1728 + m*27 + tap] * W[W_WFIN + m*96 + k];
    W[W_WP + i] = acc;
  } else if(i < 83808){
    int j = i - 82944;
    int tap = j/32, oc = j%32;
    float acc = 0.f;
    for(int m=0;m<64;m++) acc += W[W_C0W + oc*1728 + m*27 + tap] * W[W_BFIN + m];
    W[W_TB + tap*32 + oc] = acc;
  }
}

__global__ __launch_bounds__(256) void k_packb1(float* __restrict__ W){
  int i = blockIdx.x*256 + threadIdx.x;
  if(i >= 82944) return;
  int j = i&7; int lane = (i>>3)&63; int frag = i>>9;
  int nt = frag&1; int tkt = frag>>1; int kt = tkt%3; int tap = tkt/3;
  int oc = nt*16 + (lane&15);
  int k  = kt*32 + ((lane>>4)<<3) + j;
  ((bf16*)(W + W_WB1))[i] = __float2bfloat16(W[W_WP + oc*2592 + k*27 + tap]);
}
__global__ __launch_bounds__(256) void k_packb2(float* __restrict__ W){
  int i = blockIdx.x*256 + threadIdx.x;
  if(i >= 27648) return;
  int j = i&7; int lane = (i>>3)&63; int frag = i>>9;
  int nt = frag&1; int tap = frag>>1;
  int oc = nt*16 + (lane&15);
  int ic = ((lane>>4)<<3) + j;
  ((bf16*)(W + W_WB2))[i] = __float2bfloat16(W[W_C1W + oc*864 + ic*27 + tap]);
}

// pack generic 1x1 weights [48][cin] -> B frags [kt][nt][lane][8], K zero-padded
__global__ __launch_bounds__(256) void k_packc(float* __restrict__ W, int srcoff, int cin, int ktc, int dstoff){
  int i = blockIdx.x*256 + threadIdx.x;
  if(i >= ktc*1536) return;
  int j=i&7, lane=(i>>3)&63, frag=i>>9;
  int nt = frag%3, kt = frag/3;
  int oc = nt*16 + (lane&15);
  int k  = kt*32 + ((lane>>4)<<3) + j;
  float v = (k < cin) ? W[srcoff + oc*cin + k] : 0.f;
  ((bf16*)(W + dstoff))[i] = __float2bfloat16(v);
}
// pack W1P [8 par][48 oc][64 c] -> frags [par][kt][nt][lane][8]
__global__ __launch_bounds__(256) void k_packi1(float* __restrict__ W){
  int i = blockIdx.x*256 + threadIdx.x;
  if(i >= 24576) return;
  int j=i&7, lane=(i>>3)&63, frag=i>>9;   // frag 0..47
  int par = frag/6, rem = frag%6;
  int kt = rem/3, nt = rem%3;
  int oc = nt*16 + (lane&15);
  int k  = kt*32 + ((lane>>4)<<3) + j;
  ((bf16*)(W + W_WBI))[i] = __float2bfloat16(W[W_W1P + par*3072 + oc*64 + k]);
}

// ---------------- i1 MFMA: folded deconv+w1, x (NCDHW mix) -> O1 NHWC 48ch + stats set0
__global__ __launch_bounds__(256) void k_i1mm(const void* __restrict__ x, const float* __restrict__ W,
    bf16* __restrict__ out, float* __restrict__ stato, const float* __restrict__ flag)
{
  const int f = (int)flag[0];
  const int tid = threadIdx.x, wid = tid>>6, lane = tid&63;
  const int w = blockIdx.x*4 + wid;            // < 3456
  const int b = w/864, t = w%864;
  const int vc0 = t*16;                        // coarse voxel base (13824 per batch)
  const int m = lane&15, quad = lane>>4;
  const short8x* wbI = (const short8x*)(W + W_WBI);

  short8x ah[2], al[2];
  #pragma unroll
  for(int kt=0;kt<2;kt++){
    short hh[8], ll[8];
    #pragma unroll
    for(int j=0;j<8;j++){
      int k = kt*32 + quad*8 + j;
      float v = ldmix(x, ((size_t)(b*64 + k))*13824 + vc0 + m, f);
      bf16 h = __float2bfloat16(v);
      float hf = __bfloat162float(h);
      bf16 l = __float2bfloat16(v - hf);
      __builtin_memcpy(&hh[j], &h, 2); __builtin_memcpy(&ll[j], &l, 2);
    }
    __builtin_memcpy(&ah[kt], hh, 16); __builtin_memcpy(&al[kt], ll, 16);
  }

  f32x4 acc[8][3];
  #pragma unroll
  for(int p=0;p<8;p++)
    #pragma unroll
    for(int nt=0;nt<3;nt++) acc[p][nt] = (f32x4){0.f,0.f,0.f,0.f};

  #pragma unroll
  for(int par=0;par<8;par++){
    #pragma unroll
    for(int kt=0;kt<2;kt++){
      #pragma unroll
      for(int nt=0;nt<3;nt++){
        short8x bfr = wbI[(size_t)((par*2+kt)*3+nt)*64 + lane];
        acc[par][nt] = __builtin_amdgcn_mfma_f32_16x16x32_bf16(ah[kt], bfr, acc[par][nt], 0,0,0);
        acc[par][nt] = __builtin_amdgcn_mfma_f32_16x16x32_bf16(al[kt], bfr, acc[par][nt], 0,0,0);
      }
    }
  }

  // epilogue: bias + stats + LDS repack -> vector global stores
  __shared__ bf16 lds[4][128][48];
  __shared__ float sred[4][12];
  const float* bp = W + W_B1F;
  float sl[3] = {0,0,0}, ssl[3] = {0,0,0};
  #pragma unroll
  for(int nt=0;nt<3;nt++){
    int oc = nt*16 + m;
    float bias = bp[oc];
    #pragma unroll
    for(int par=0;par<8;par++){
      #pragma unroll
      for(int r=0;r<4;r++){
        float v = acc[par][nt][r] + bias;
        int vid = (quad*4+r)*8 + par;
        lds[wid][vid][oc] = __float2bfloat16(v);
        sl[nt] += v; ssl[nt] += v*v;
      }
    }
  }
  #pragma unroll
  for(int nt=0;nt<3;nt++){
    float a = sl[nt], s2 = ssl[nt];
    a += __shfl_xor(a,16); s2 += __shfl_xor(s2,16);
    a += __shfl_xor(a,32); s2 += __shfl_xor(s2,32);
    a += __shfl_xor(a,1);  s2 += __shfl_xor(s2,1);
    a += __shfl_xor(a,2);  s2 += __shfl_xor(s2,2);
    a += __shfl_xor(a,4);  s2 += __shfl_xor(s2,4);
    if(quad==0 && (m&7)==0){
      int g = nt*2 + (m>>3);
      sred[wid][g] = a; sred[wid][6+g] = s2;
    }
  }
  // wave-internal LDS read (no barrier needed) -> 96B vector stores per voxel
  #pragma unroll
  for(int i=0;i<2;i++){
    int vid = lane*2 + i;
    int mm = vid>>3, par = vid&7;
    int vcm = vc0 + mm;
    int xh = vcm%24, yh = (vcm/24)%24, zh = vcm/576;
    int pz = par>>2, py = (par>>1)&1, px = par&1;
    size_t vout = (size_t)(2*zh+pz)*2304 + (2*yh+py)*48 + (2*xh+px);
    uint4x* dst = (uint4x*)(out + ((size_t)b*NVLL + vout)*48);
    const uint4x* srcl = (const uint4x*)&lds[wid][vid][0];
    #pragma unroll
    for(int q=0;q<6;q++) dst[q] = srcl[q];
  }
  __syncthreads();
  if(tid < 12){
    int bb = (blockIdx.x*4)/864;
    float v = sred[0][tid]+sred[1][tid]+sred[2][tid]+sred[3][tid];
    int g = tid%6, kind = tid/6;
    atomicAdd(&stato[(blockIdx.x&(NSH-1))*STSTRIDE + (kind?24:0) + bb*6+g], v);
  }
}

// ---------------- MFMA 1x1 conv: NHWC(48) or NCDHW-mix(32) in -> NHWC 48 out + GN stats
// GNIN: apply GN(set_in)+leaky(0.1) to input channels during A-frag build (bf16 path only)
template<int CIN, bool MIX, bool GNIN>
__global__ __launch_bounds__(256) void k_c1mm(const void* in, const bf16* __restrict__ wbf,
    const float* __restrict__ bias, bf16* out, float* __restrict__ stato, int set_out,
    const float* __restrict__ stats_in, int set_in,
    const float* __restrict__ gamma, const float* __restrict__ beta,
    const float* __restrict__ flag)
{
  constexpr int KT = (CIN+31)/32;
  const int f = MIX ? (int)flag[0] : 0;
  const int tid = threadIdx.x, wid = tid>>6, lane = tid&63;
  const int w = blockIdx.x*4 + wid;            // < 27648
  const size_t v0g = (size_t)w*16;
  const int b = (int)(v0g/NVLL);
  const size_t v0l = v0g - (size_t)b*NVLL;
  const int m = lane&15, quad = lane>>4;
  const short8x* wb8 = (const short8x*)wbf;
  const short8x zf = {0,0,0,0,0,0,0,0};

  __shared__ float gsm[12];
  if constexpr(GNIN){
    if(tid < 12){
      int bb = (int)(((size_t)blockIdx.x*64)/NVLL);
      int kind = tid/6, g = tid%6;
      int off = set_in*48 + (kind?24:0) + bb*6+g;
      float s = 0.f;
      for(int sh=0; sh<NSH; sh++) s += stats_in[sh*STSTRIDE + off];
      gsm[tid] = s;
    }
    __syncthreads();
  }
  float gm[GNIN?6:1], gr[GNIN?6:1];
  if constexpr(GNIN){
    const float invN = 1.0f/(8.0f*(float)NV);
    #pragma unroll
    for(int g=0;g<6;g++){
      float mm = gsm[g]*invN;
      float var = gsm[6+g]*invN - mm*mm;
      gm[g] = mm; gr[g] = rsqrtf(var + 1e-5f);
    }
  }

  short8x afh[KT], afl[MIX?KT:1];
  #pragma unroll
  for(int kt=0;kt<KT;kt++){
    if constexpr(MIX){
      short hh[8], ll[8];
      #pragma unroll
      for(int j=0;j<8;j++){
        int ch = kt*32 + quad*8 + j;
        float v = ldmix(in, ((size_t)(b*CIN+ch))*NVLL + v0l + m, f);
        bf16 h = __float2bfloat16(v);
        float hf = __bfloat162float(h);
        bf16 l = __float2bfloat16(v - hf);
        __builtin_memcpy(&hh[j], &h, 2); __builtin_memcpy(&ll[j], &l, 2);
      }
      __builtin_memcpy(&afh[kt], hh, 16); __builtin_memcpy(&afl[kt], ll, 16);
    } else {
      int k0 = kt*32 + quad*8;
      if(k0 < CIN){
        short8x a = *(const short8x*)((const bf16*)in + (v0g + m)*48 + k0);
        if constexpr(GNIN){
          short hh[8];
          #pragma unroll
          for(int j=0;j<8;j++){
            int ch = k0 + j;
            short raw = a[j];
            unsigned int u = ((unsigned int)(unsigned short)raw) << 16;
            float xv; __builtin_memcpy(&xv, &u, 4);
            int g = ch>>3;
            xv = (xv - gm[g])*gr[g]*gamma[ch] + beta[ch];
            xv = xv < 0.f ? 0.1f*xv : xv;
            hh[j] = (short)bfb(xv);
          }
          __builtin_memcpy(&a, hh, 16);
        }
        afh[kt] = a;
      } else afh[kt] = zf;
    }
  }

  f32x4 acc[3];
  #pragma unroll
  for(int nt=0;nt<3;nt++) acc[nt] = (f32x4){0.f,0.f,0.f,0.f};
  #pragma unroll
  for(int kt=0;kt<KT;kt++){
    #pragma unroll
    for(int nt=0;nt<3;nt++){
      short8x bfr = wb8[(size_t)(kt*3+nt)*64 + lane];
      acc[nt] = __builtin_amdgcn_mfma_f32_16x16x32_bf16(afh[kt], bfr, acc[nt], 0,0,0);
      if constexpr(MIX)
        acc[nt] = __builtin_amdgcn_mfma_f32_16x16x32_bf16(afl[kt], bfr, acc[nt], 0,0,0);
    }
  }

  __shared__ bf16 lds[4][16][48];
  __shared__ float sred[4][12];
  float sl[3] = {0,0,0}, ssl[3] = {0,0,0};
  #pragma unroll
  for(int nt=0;nt<3;nt++){
    int oc = nt*16 + m;
    float bv = bias[oc];
    #pragma unroll
    for(int r=0;r<4;r++){
      float v = acc[nt][r] + bv;
      lds[wid][quad*4+r][oc] = __float2bfloat16(v);
      sl[nt] += v; ssl[nt] += v*v;
    }
  }
  #pragma unroll
  for(int nt=0;nt<3;nt++){
    float a = sl[nt], s2 = ssl[nt];
    a += __shfl_xor(a,16); s2 += __shfl_xor(s2,16);
    a += __shfl_xor(a,32); s2 += __shfl_xor(s2,32);
    a += __shfl_xor(a,1);  s2 += __shfl_xor(s2,1);
    a += __shfl_xor(a,2);  s2 += __shfl_xor(s2,2);
    a += __shfl_xor(a,4);  s2 += __shfl_xor(s2,4);
    if(quad==0 && (m&7)==0){
      int g = nt*2 + (m>>3);
      sred[wid][g] = a; sred[wid][6+g] = s2;
    }
  }
  if(lane < 16){
    uint4x* dst = (uint4x*)(out + (v0g + lane)*48);
    const uint4x* srcl = (const uint4x*)&lds[wid][lane][0];
    #pragma unroll
    for(int q=0;q<6;q++) dst[q] = srcl[q];
  }
  __syncthreads();
  if(tid < 12){
    int bb = (int)(((size_t)(blockIdx.x*4)*16)/NVLL);
    float v = sred[0][tid]+sred[1][tid]+sred[2][tid]+sred[3][tid];
    int g = tid%6, kind = tid/6;
    atomicAdd(&stato[(blockIdx.x&(NSH-1))*STSTRIDE + set_out*48 + (kind?24:0) + bb*6+g], v);
  }
}

// ---------------- GN apply + leaky(0.1), NHWC vectorized, shard-summed stats -----------
__global__ __launch_bounds__(256) void k_gn_apply(bf16* buf, const float* __restrict__ stats, int set,
    const float* __restrict__ gamma, const float* __restrict__ beta)
{
  const int v = blockIdx.x*256 + threadIdx.x;
  const int b = blockIdx.y;
  __shared__ float sm[12];
  if(threadIdx.x < 12){
    int kind = threadIdx.x/6, g = threadIdx.x%6;
    int off = set*48 + (kind?24:0) + b*6+g;
    float s = 0.f;
    for(int sh=0; sh<NSH; sh++) s += stats[sh*STSTRIDE + off];
    sm[threadIdx.x] = s;
  }
  __syncthreads();
  const float invN = 1.0f/(8.0f*(float)NV);
  float m[6], rs[6];
  #pragma unroll
  for(int g=0;g<6;g++){
    float mm = sm[g]*invN;
    float var = sm[6+g]*invN - mm*mm;
    m[g] = mm; rs[g] = rsqrtf(var + 1e-5f);
  }
  uint4x* p4 = (uint4x*)(buf + ((size_t)b*NVLL + v)*48);
  uint4x w6[6];
  #pragma unroll
  for(int q=0;q<6;q++) w6[q] = p4[q];
  unsigned int* wu = (unsigned int*)w6;
  #pragma unroll
  for(int c2=0;c2<24;c2++){
    int c0 = 2*c2;
    float x0 = lo2f(wu[c2]), x1 = hi2f(wu[c2]);
    int g0 = c0>>3, g1 = (c0+1)>>3;
    x0 = (x0 - m[g0])*rs[g0]*gamma[c0] + beta[c0];
    x1 = (x1 - m[g1])*rs[g1]*gamma[c0+1] + beta[c0+1];
    x0 = x0 < 0.f ? 0.1f*x0 : x0;
    x1 = x1 < 0.f ? 0.1f*x1 : x1;
    wu[c2] = pk2(x0, x1);
  }
  #pragma unroll
  for(int q=0;q<6;q++) p4[q] = w6[q];
}

// ---------------- pool 48^3 -> 6^3 (vectorized NHWC loads) ----------------
__global__ __launch_bounds__(512) void k_pool2(const bf16* __restrict__ s0, const bf16* __restrict__ s1,
    float* __restrict__ d0, float* __restrict__ d1)
{
  const int which = blockIdx.y;
  const bf16* src = which ? s1 : s0;
  float*      dst = which ? d1 : d0;
  const int cell = blockIdx.x % 216, b = blockIdx.x/216;
  const int tid = threadIdx.x;
  const int cz=cell/36, cy=(cell/6)%6, cx=cell%6;
  const int dz=tid>>6, dy=(tid>>3)&7, dx=tid&7;
  const size_t vox = (size_t)(cz*8+dz)*2304 + (cy*8+dy)*48 + (cx*8+dx);
  const uint4x* p4 = (const uint4x*)(src + ((size_t)b*NVLL + vox)*48);
  uint4x w6[6];
  #pragma unroll
  for(int q=0;q<6;q++) w6[q] = p4[q];
  const unsigned int* wu = (const unsigned int*)w6;
  float val[48];
  #pragma unroll
  for(int c2=0;c2<24;c2++){ val[2*c2] = lo2f(wu[c2]); val[2*c2+1] = hi2f(wu[c2]); }
  __shared__ float rmax[8][48], rsum[8][48];
  const int wid=tid>>6, lane=tid&63;
  #pragma unroll
  for(int o=0;o<48;o++){
    float mx=val[o], sm=val[o];
    #pragma unroll
    for(int s=32;s>=1;s>>=1){ mx=fmaxf(mx,__shfl_xor(mx,s)); sm+=__shfl_xor(sm,s); }
    if(lane==0){ rmax[wid][o]=mx; rsum[wid][o]=sm; }
  }
  __syncthreads();
  if(tid<48){
    float mx=rmax[0][tid], sm=rsum[0][tid];
    #pragma unroll
    for(int w2=1;w2<8;w2++){ mx=fmaxf(mx,rmax[w2][tid]); sm+=rsum[w2][tid]; }
    dst[(size_t)(b*48+tid)*216 + cell] = mx + sm*(1.f/512.f);
  }
}

// ------- fused conv1x1(concat(xe, folded-x0)) + pool -> pkv, wave-uniform parity -------
// block = (b, cell); wave wid = parity; lane = 4x4x4 coarse offset in cell
__global__ __launch_bounds__(512) void k_poolfuse(const void* __restrict__ xe, const void* __restrict__ x,
    const float* __restrict__ W, float* __restrict__ pkv, const float* __restrict__ flag)
{
  const int f = (int)flag[0];
  const int cell = blockIdx.x % 216;
  const int b = blockIdx.x / 216;
  const int tid = threadIdx.x;
  const int wid = tid>>6, lane = tid&63;         // wid = parity 0..7
  const int pz = wid>>2, py = (wid>>1)&1, px = wid&1;
  const int cz = cell/36, cy = (cell/6)%6, cx = cell%6;
  const int czi = lane>>4, cyi = (lane>>2)&3, cxi = lane&3;
  const int zc = cz*4+czi, yc = cy*4+cyi, xc = cx*4+cxi;
  const int vh = zc*576 + yc*24 + xc;
  const size_t voff = (size_t)(2*zc+pz)*2304 + (2*yc+py)*48 + (2*xc+px);
  float xev[32], xrv[64];
  #pragma unroll
  for(int c=0;c<32;c++) xev[c] = ldmix(xe, ((size_t)(b*32+c))*NVLL + voff, f);
  #pragma unroll
  for(int c=0;c<64;c++) xrv[c] = ldmix(x, (size_t)(b*64+c)*13824 + vh, f);
  const float* wf  = W + W_WF;
  const float* wfp = W + W_WFP + wid*3072;       // wave-uniform -> scalar loads
  const float* bff = W + W_BFF;
  __shared__ float rmax[8][48];
  __shared__ float rsum[8][48];
  #pragma unroll
  for(int o=0;o<48;o++){
    float acc = bff[o];
    #pragma unroll
    for(int c=0;c<32;c++) acc += wf[o*64+c]*xev[c];
    #pragma unroll
    for(int c=0;c<64;c++) acc += wfp[o*64+c]*xrv[c];
    float mx = acc, sm = acc;
    #pragma unroll
    for(int s=32;s>=1;s>>=1){ mx = fmaxf(mx, __shfl_xor(mx,s)); sm += __shfl_xor(sm,s); }
    if(lane==0){ rmax[wid][o] = mx; rsum[wid][o] = sm; }
  }
  __syncthreads();
  if(tid < 48){
    float mx = rmax[0][tid], sm = rsum[0][tid];
    #pragma unroll
    for(int w2=1;w2<8;w2++){ mx = fmaxf(mx, rmax[w2][tid]); sm += rsum[w2][tid]; }
    pkv[((size_t)(b*48+tid))*216 + cell] = mx + sm*(1.f/512.f);
  }
}

// ---------------- linear cross-attention ----------------
__global__ __launch_bounds__(256) void k_attn(const float* __restrict__ p1, const float* __restrict__ p2,
    const float* __restrict__ pkv, const float* __restrict__ W, float* __restrict__ a1, float* __restrict__ a2)
{
  const int which = blockIdx.x, b = blockIdx.y;
  const float* wb = W + W_ATT + which*9408;
  const float* wq = wb;        const float* bq = wb+2304;
  const float* wk = wb+2352;   const float* bk = wb+4656;
  const float* wv = wb+4704;   const float* bv = wb+7008;
  const float* wo = wb+7056;   const float* bo = wb+9360;
  const float* q   = which ? p2 : p1;
  float*       aout= which ? a2 : a1;
  const float* kvb = pkv + (size_t)b*48*216;
  const float* qb  = q   + (size_t)b*48*216;
  __shared__ float kh[216*48];
  __shared__ float ctx[288];
  const int tid = threadIdx.x;

  if(tid < 216){
    float kvr[48];
    #pragma unroll
    for(int c=0;c<48;c++) kvr[c] = kvb[c*216 + tid];
    #pragma unroll
    for(int o=0;o<48;o++){
      float acc = bk[o];
      #pragma unroll
      for(int c=0;c<48;c++) acc += kvr[c]*wk[o*48+c];
      kh[tid*48+o] = acc;
    }
  }
  __syncthreads();
  if(tid < 48){
    float mx = -1e30f;
    for(int n=0;n<216;n++) mx = fmaxf(mx, kh[n*48+tid]);
    float s = 0.f;
    for(int n=0;n<216;n++){ float e = __expf(kh[n*48+tid]-mx); kh[n*48+tid] = e; s += e; }
    float inv = 1.f/s;
    for(int n=0;n<216;n++) kh[n*48+tid] *= inv;
  }
  __syncthreads();
  if(tid < 48){
    int h = tid/6, e = tid%6;
    float cacc[6] = {0,0,0,0,0,0};
    for(int n=0;n<216;n++){
      float vh = bv[h*6+e];
      #pragma unroll
      for(int c=0;c<48;c++) vh += kvb[c*216+n]*wv[(h*6+e)*48+c];
      #pragma unroll
      for(int d=0;d<6;d++) cacc[d] += kh[n*48 + h*6+d]*vh;
    }
    #pragma unroll
    for(int d=0;d<6;d++) ctx[(h*6+d)*6+e] = cacc[d];
  }
  __syncthreads();
  if(tid < 216){
    int n = tid;
    float qr[48];
    #pragma unroll
    for(int c=0;c<48;c++) qr[c] = qb[c*216 + n];
    float qh[48];
    #pragma unroll
    for(int o=0;o<48;o++){
      float acc = bq[o];
      #pragma unroll
      for(int c=0;c<48;c++) acc += qr[c]*wq[o*48+c];
      qh[o] = acc;
    }
    #pragma unroll
    for(int h=0;h<8;h++){
      float mx = qh[h*6];
      #pragma unroll
      for(int d=1;d<6;d++) mx = fmaxf(mx, qh[h*6+d]);
      float s = 0.f;
      #pragma unroll
      for(int d=0;d<6;d++){ float e = __expf(qh[h*6+d]-mx); qh[h*6+d] = e; s += e; }
      float inv = 1.f/s;
      #pragma unroll
      for(int d=0;d<6;d++) qh[h*6+d] *= inv;
    }
    float ov[48];
    #pragma unroll
    for(int h=0;h<8;h++){
      #pragma unroll
      for(int e=0;e<6;e++){
        float acc = 0.f;
        #pragma unroll
        for(int d=0;d<6;d++) acc += qh[h*6+d]*ctx[(h*6+d)*6+e];
        ov[h*6+e] = acc;
      }
    }
    #pragma unroll
    for(int o=0;o<48;o++){
      float acc = bo[o];
      #pragma unroll
      for(int c=0;c<48;c++) acc += ov[c]*wo[o*48+c];
      aout[((size_t)(b*48+o))*216 + n] = acc;
    }
  }
}

// ---------------- gate: i1 *= sig(up(a1)), i2 *= sig(up(a2)), vectorized ----------------
__device__ inline void interp1(int u, int& i0, int& i1, float& t){
  float pos = u * (5.0f/47.0f);
  float f = floorf(pos);
  i0 = (int)f; if(i0 > 5) i0 = 5;
  i1 = i0+1 > 5 ? 5 : i0+1;
  t = pos - f; if(t < 0.f) t = 0.f; if(t > 1.f) t = 1.f;
}

__global__ __launch_bounds__(256) void k_gate(bf16* i1b, bf16* i2b,
    const float* __restrict__ a1, const float* __restrict__ a2)
{
  const int v = blockIdx.x*256 + threadIdx.x;
  const int b = blockIdx.y;
  const int x = v % 48, y = (v/48) % 48, z = v/2304;
  int xi0,xi1,yi0,yi1,zi0,zi1; float xt,yt,zt;
  interp1(x,xi0,xi1,xt); interp1(y,yi0,yi1,yt); interp1(z,zi0,zi1,zt);
  int off[8]; float cw[8];
  off[0]=zi0*36+yi0*6+xi0; cw[0]=(1-zt)*(1-yt)*(1-xt);
  off[1]=zi0*36+yi0*6+xi1; cw[1]=(1-zt)*(1-yt)*xt;
  off[2]=zi0*36+yi1*6+xi0; cw[2]=(1-zt)*yt*(1-xt);
  off[3]=zi0*36+yi1*6+xi1; cw[3]=(1-zt)*yt*xt;
  off[4]=zi1*36+yi0*6+xi0; cw[4]=zt*(1-yt)*(1-xt);
  off[5]=zi1*36+yi0*6+xi1; cw[5]=zt*(1-yt)*xt;
  off[6]=zi1*36+yi1*6+xi0; cw[6]=zt*yt*(1-xt);
  off[7]=zi1*36+yi1*6+xi1; cw[7]=zt*yt*xt;
  const float* A1b = a1 + (size_t)b*48*216;
  const float* A2b = a2 + (size_t)b*48*216;

  uint4x* p14 = (uint4x*)(i1b + ((size_t)b*NVLL + v)*48);
  uint4x* p24 = (uint4x*)(i2b + ((size_t)b*NVLL + v)*48);
  uint4x w6[6];
  #pragma unroll
  for(int q=0;q<6;q++) w6[q] = p14[q];
  unsigned int* wu = (unsigned int*)w6;
  #pragma unroll
  for(int c2=0;c2<24;c2++){
    int c0 = 2*c2;
    float s0 = 0.f, s1 = 0.f;
    #pragma unroll
    for(int k=0;k<8;k++){ s0 += cw[k]*A1b[c0*216+off[k]]; s1 += cw[k]*A1b[(c0+1)*216+off[k]]; }
    s0 = 1.f/(1.f + __expf(-s0));
    s1 = 1.f/(1.f + __expf(-s1));
    wu[c2] = pk2(s0*lo2f(wu[c2]), s1*hi2f(wu[c2]));
  }
  #pragma unroll
  for(int q=0;q<6;q++) p14[q] = w6[q];

  #pragma unroll
  for(int q=0;q<6;q++) w6[q] = p24[q];
  #pragma unroll
  for(int c2=0;c2<24;c2++){
    int c0 = 2*c2;
    float s0 = 0.f, s1 = 0.f;
    #pragma unroll
    for(int k=0;k<8;k++){ s0 += cw[k]*A2b[c0*216+off[k]]; s1 += cw[k]*A2b[(c0+1)*216+off[k]]; }
    s0 = 1.f/(1.f + __expf(-s0));
    s1 = 1.f/(1.f + __expf(-s1));
    wu[c2] = pk2(s0*lo2f(wu[c2]), s1*hi2f(wu[c2]));
  }
  #pragma unroll
  for(int q=0;q<6;q++) p24[q] = w6[q];
}

// ---------------- MFMA implicit-GEMM 3x3x3 conv, block-reduced sharded stats -----------
template<int KT, bool TWO, bool USETB>
__global__ __launch_bounds__(256) void k_conv3m(
    const bf16* __restrict__ in0, const bf16* __restrict__ in1,
    const bf16* __restrict__ wb, const float* __restrict__ tb, const float* __restrict__ cb,
    bf16* __restrict__ outp, float* __restrict__ stato, int sOut, int bidx, int onhwc)
{
  const int tid = threadIdx.x;
  const int wid = tid>>6, lane = tid&63;
  const int run = blockIdx.x*4 + wid;          // 6912 runs
  const int x0 = (run%3)*16, y = (run/3)%48, z = run/144;
  const int m = lane&15, quad = lane>>4;
  const int CB = TWO ? 48 : 32;
  const int k0 = quad*8;
  const short8x* wb8 = (const short8x*)wb;
  const short8x zf = {0,0,0,0,0,0,0,0};

  f32x4 acc0 = {0.f,0.f,0.f,0.f};
  f32x4 acc1 = {0.f,0.f,0.f,0.f};

  for(int dz=0; dz<3; dz++){
    int zz = z + dz - 1;
    if(zz < 0 || zz >= 48) continue;
    for(int dy=0; dy<3; dy++){
      int yy = y + dy - 1;
      if(yy < 0 || yy >= 48) continue;
      #pragma unroll
      for(int dx=0; dx<3; dx++){
        int xx = x0 + m + dx - 1;
        bool ok = (xx >= 0 && xx < 48);
        int xc = xx < 0 ? 0 : (xx > 47 ? 47 : xx);
        int vox = zz*2304 + yy*48 + xc;
        int tap = dz*9 + dy*3 + dx;
        #pragma unroll
        for(int kt=0; kt<KT; kt++){
          int kk = kt*32 + k0;
          const bf16* src; int ch;
          if(TWO){ if(kk < 48){ src = in0; ch = kk; } else { src = in1; ch = kk-48; } }
          else    { src = in0; ch = kk; }
          short8x af = *(const short8x*)(src + (size_t)vox*CB + ch);
          if(!ok) af = zf;
          short8x b0 = wb8[ (size_t)((tap*KT + kt)*2 + 0)*64 + lane ];
          short8x b1 = wb8[ (size_t)((tap*KT + kt)*2 + 1)*64 + lane ];
          acc0 = __builtin_amdgcn_mfma_f32_16x16x32_bf16(af, b0, acc0, 0,0,0);
          acc1 = __builtin_amdgcn_mfma_f32_16x16x32_bf16(af, b1, acc1, 0,0,0);
        }
      }
    }
  }

  const int oc0 = m, oc1 = 16 + m;
  float s0=0.f, ss0=0.f, s1=0.f, ss1=0.f;
  #pragma unroll
  for(int r=0;r<4;r++){
    int mv = quad*4 + r;
    int xr = x0 + mv;
    float b0v = cb[oc0], b1v = cb[oc1];
    if constexpr(USETB){
      #pragma unroll
      for(int t=0;t<27;t++){
        int tdz = t/9, tdy = (t/3)%3, tdx = t%3;
        int zz = z+tdz-1, yy = y+tdy-1, xx = xr+tdx-1;
        if(zz>=0 && zz<48 && yy>=0 && yy<48 && xx>=0 && xx<48){
          b0v += tb[t*32+oc0]; b1v += tb[t*32+oc1];
        }
      }
    }
    float v0 = acc0[r] + b0v;
    float v1 = acc1[r] + b1v;
    size_t vox = (size_t)z*2304 + y*48 + xr;
    if(onhwc){
      outp[vox*32 + oc0] = __float2bfloat16(v0);
      outp[vox*32 + oc1] = __float2bfloat16(v1);
    } else {
      outp[(size_t)oc0*NVLL + vox] = __float2bfloat16(v0);
      outp[(size_t)oc1*NVLL + vox] = __float2bfloat16(v1);
    }
    s0 += v0; ss0 += v0*v0; s1 += v1; ss1 += v1*v1;
  }
  s0 += __shfl_xor(s0,16); ss0 += __shfl_xor(ss0,16); s1 += __shfl_xor(s1,16); ss1 += __shfl_xor(ss1,16);
  s0 += __shfl_xor(s0,32); ss0 += __shfl_xor(ss0,32); s1 += __shfl_xor(s1,32); ss1 += __shfl_xor(ss1,32);
  __shared__ float csum[4][32], css[4][32];
  if(quad==0){
    csum[wid][oc0]=s0; css[wid][oc0]=ss0;
    csum[wid][oc1]=s1; css[wid][oc1]=ss1;
  }
  __syncthreads();
  if(tid < 64){
    int oc = tid&31, kind = tid>>5;
    float v = kind ? (css[0][oc]+css[1][oc]+css[2][oc]+css[3][oc])
                   : (csum[0][oc]+csum[1][oc]+csum[2][oc]+csum[3][oc]);
    atomicAdd(&stato[(blockIdx.x&(NSH-1))*STSTRIDE + sOut + (kind?128:0) + bidx*32 + oc], v);
  }
}

// ---------------- IN + leaky(0.01) on h1 (NHWC), shard-summed stats --------------------
struct P4 { bf16* p[4]; };
__global__ __launch_bounds__(256) void k_inleak(P4 h1, const float* __restrict__ stats){
  int gid = blockIdx.x*256 + threadIdx.x;      // grid 1728: thread per voxel
  int b = gid/NV; int v = gid - b*NV;
  __shared__ float sm2[64];
  if(threadIdx.x < 64){
    int oc = threadIdx.x&31, kind = threadIdx.x>>5;
    int off = 192 + (kind?128:0) + b*32 + oc;
    float s = 0.f;
    for(int sh=0; sh<NSH; sh++) s += stats[sh*STSTRIDE + off];
    sm2[threadIdx.x] = s;
  }
  __syncthreads();
  const float invN = 1.f/(float)NV;
  uint4x* p4 = (uint4x*)(h1.p[b] + (size_t)v*32);
  uint4x w4[4];
  #pragma unroll
  for(int q=0;q<4;q++) w4[q] = p4[q];
  unsigned int* wu = (unsigned int*)w4;
  #pragma unroll
  for(int c2=0;c2<16;c2++){
    int c0 = 2*c2;
    float m0 = sm2[c0]*invN,   m1 = sm2[c0+1]*invN;
    float r0 = rsqrtf(sm2[32+c0]*invN - m0*m0 + 1e-5f);
    float r1 = rsqrtf(sm2[32+c0+1]*invN - m1*m1 + 1e-5f);
    float x0 = (lo2f(wu[c2]) - m0)*r0;
    float x1 = (hi2f(wu[c2]) - m1)*r1;
    x0 = x0 < 0.f ? 0.01f*x0 : x0;
    x1 = x1 < 0.f ? 0.01f*x1 : x1;
    wu[c2] = pk2(x0, x1);
  }
  #pragma unroll
  for(int q=0;q<4;q++) p4[q] = w4[q];
}

// ---------------- final IN + leaky(0.01): h2 slabs (NCHW) -> d_out, shard-summed -------
__global__ __launch_bounds__(256) void k_in_final(P4 h2, const float* __restrict__ stats,
    void* out, const float* __restrict__ flag)
{
  const int f = (int)flag[0];
  int gid = blockIdx.x*256 + threadIdx.x;      // grid 6912 blocks, 8 elem/thread
  size_t i8 = (size_t)gid*8;
  int b = (int)(i8/(NV*32)); int j = (int)(i8 - (size_t)b*(NV*32));
  int c = j/NV;
  size_t i80 = (size_t)(blockIdx.x*256)*8;
  int b0 = (int)(i80/(NV*32)); int j0 = (int)(i80 - (size_t)b0*(NV*32));
  int c0 = j0/NV;
  __shared__ float sm2[4];
  if(threadIdx.x < 4){
    int dc = threadIdx.x>>1, kind = threadIdx.x&1;
    int cc = c0+dc > 31 ? 31 : c0+dc;
    int off = 448 + (kind?128:0) + b0*32 + cc;
    float s = 0.f;
    for(int sh=0; sh<NSH; sh++) s += stats[sh*STSTRIDE + off];
    sm2[threadIdx.x] = s;
  }
  __syncthreads();
  const float invN = 1.f/(float)NV;
  int dc = c - c0;
  float m = sm2[dc*2]*invN;
  float var = sm2[dc*2+1]*invN - m*m;
  float rs = rsqrtf(var + 1e-5f);
  uint4x w = *(uint4x*)(h2.p[b] + j);
  const unsigned int* wu = (const unsigned int*)&w;
  float vv[8];
  #pragma unroll
  for(int k2=0;k2<4;k2++){ vv[2*k2] = lo2f(wu[k2]); vv[2*k2+1] = hi2f(wu[k2]); }
  #pragma unroll
  for(int k=0;k<8;k++){
    float xv = (vv[k]-m)*rs;
    vv[k] = xv < 0.f ? 0.01f*xv : xv;
  }
  if(f){
    float* op = (float*)out + i8;
    uint4x o0, o1;
    __builtin_memcpy(&o0, &vv[0], 16);
    __builtin_memcpy(&o1, &vv[4], 16);
    ((uint4x*)op)[0] = o0; ((uint4x*)op)[1] = o1;
  } else {
    unsigned int pk[4];
    #pragma unroll
    for(int k2=0;k2<4;k2++) pk[k2] = pk2(vv[2*k2], vv[2*k2+1]);
    *(uint4x*)((bf16*)out + i8) = *(uint4x*)pk;
  }
}

// ==========================================================================
extern "C" void kernel_launch(void* const* d_in, const int* in_sizes, int n_in,
                              void* d_out, int out_size, void* d_ws, size_t ws_size,
                              hipStream_t stream)
{
  (void)in_sizes; (void)n_in; (void)out_size; (void)ws_size;
  char* base = (char*)d_ws;
  const void* x  = d_in[0];
  const void* xe = d_in[1];

  float* SM  = (float*)base;
  float* P1  = SM + SM_P1;
  float* P2  = SM + SM_P2;
  float* PKV = SM + SM_PKV;
  float* A1  = SM + SM_A1;
  float* A2  = SM + SM_A2;
  float* ST  = SM + SM_ST;
  float* W   = SM + SM_W;
  float* FL  = SM + SM_FL;
  bf16*  O1  = (bf16*)(base + BOFF_O1);
  bf16*  O2  = (bf16*)(base + BOFF_O2);

  P4 H1, H2;
  H1.p[0] = (bf16*)(base + BOFF_SP);
  H1.p[1] = (bf16*)(base + BOFF_O1);
  H1.p[2] = (bf16*)(base + BOFF_O1 + SLOT48);
  H1.p[3] = (bf16*)(base + BOFF_O1 + 2*SLOT48);
  for(int b=0;b<4;b++) H2.p[b] = (bf16*)(base + BOFF_O2 + (size_t)b*SLOT48);

  k_detect<<<1, 256, 0, stream>>>(xe, FL);
  k_zero<<<(NSH*STSTRIDE+255)/256, 256, 0, stream>>>(ST);

  PtrTab pt;
  for(int i=0;i<36;i++) pt.p[i] = d_in[i+2];
  k_prep<<<(W_TOTAL+255)/256, 256, 0, stream>>>(pt, W, FL);
  k_fold <<<193, 256, 0, stream>>>(W);
  k_fold2<<<328, 256, 0, stream>>>(W);
  k_packb1<<<324, 256, 0, stream>>>(W);
  k_packb2<<<108, 256, 0, stream>>>(W);
  k_packc<<<6,  256, 0, stream>>>(W, W_W2, 32, 1, W_WB3);
  k_packc<<<12, 256, 0, stream>>>(W, W_W3, 48, 2, W_WB4);
  k_packc<<<12, 256, 0, stream>>>(W, W_W4, 48, 2, W_WB5);
  k_packi1<<<96, 256, 0, stream>>>(W);

  const float* gam = W + W_GNG;
  const float* bet = W + W_GNB;

  // i1 branch -> O1 (NHWC): MFMA deconv+w1 (stats 0), MFMA w3 w/ fused GN(0) (stats 1), GN(1)
  k_i1mm<<<864, 256, 0, stream>>>(x, W, O1, ST, FL);
  k_c1mm<48,false,true ><<<6912, 256, 0, stream>>>(O1, (const bf16*)(W+W_WB4), W+W_B3, O1, ST, 1, ST, 0, gam, bet, FL);
  k_gn_apply<<<dim3(432,4), 256, 0, stream>>>(O1, ST, 1, gam, bet);

  // i2 branch -> O2 (NHWC): MFMA w2 mix (stats 2), MFMA w4 w/ fused GN(2) (stats 3), GN(3)
  k_c1mm<32,true ,false><<<6912, 256, 0, stream>>>(xe, (const bf16*)(W+W_WB3), W+W_B2, O2, ST, 2, ST, 0, gam, bet, FL);
  k_c1mm<48,false,true ><<<6912, 256, 0, stream>>>(O2, (const bf16*)(W+W_WB5), W+W_B4, O2, ST, 3, ST, 2, gam, bet, FL);
  k_gn_apply<<<dim3(432,4), 256, 0, stream>>>(O2, ST, 3, gam, bet);

  // pools + attention
  k_pool2<<<dim3(864,2), 512, 0, stream>>>(O1, O2, P1, P2);
  k_poolfuse<<<864, 512, 0, stream>>>(xe, x, W, PKV, FL);
  k_attn<<<dim3(2,4), 256, 0, stream>>>(P1, P2, PKV, W, A1, A2);

  // gate i1,i2 in place -> o1,o2
  k_gate<<<dim3(432,4), 256, 0, stream>>>(O1, O2, A1, A2);

  // conv#1 (folded with Wfin): 96ch NHWC -> h1 (NHWC 32ch), IN stats @192
  for(int b=0;b<4;b++){
    const bf16* o1b = O1 + (size_t)b*48*NVLL;
    const bf16* o2b = O2 + (size_t)b*48*NVLL;
    k_conv3m<3,true,true><<<1728, 256, 0, stream>>>(o1b, o2b, (const bf16*)(W+W_WB1), W+W_TB, W+W_C0B,
                                                    H1.p[b], ST, 192, b, 1);
  }
  k_inleak<<<1728, 256, 0, stream>>>(H1, ST);

  // conv#2: 32ch NHWC -> h2 (NCHW slab), IN stats @448
  for(int b=0;b<4;b++){
    k_conv3m<1,false,false><<<1728, 256, 0, stream>>>(H1.p[b], nullptr, (const bf16*)(W+W_WB2), nullptr, W+W_C1B,
                                                      H2.p[b], ST, 448, b, 0);
  }
  k_in_final<<<6912, 256, 0, stream>>>(H2, ST, d_out, FL);
}